// Round 2
// baseline (5565.604 us; speedup 1.0000x reference)
//
#include <hip/hip_runtime.h>

constexpr int IN_F = 128;
constexpr int HID  = 256;
constexpr int OUT_F = 64;

static inline int cdiv_ll(long long a, long long b) { return (int)((a + b - 1) / b); }

// ---------------- scatter-add over edges (atomic) ----------------
// idx -> (edge e, float4-chunk c). Consecutive tids share an edge ->
// gathers are row-contiguous (128B/256B segments per edge).
// NOTE: harness delivers integer inputs as int32: src = ei[e], dst = ei[E+e].
__global__ __launch_bounds__(256) void scatter_add_kernel(
    const float4* __restrict__ x, const int* __restrict__ ei,
    float* __restrict__ agg, int E, int chunks_log2)
{
    long long idx = (long long)blockIdx.x * blockDim.x + threadIdx.x;
    long long total = (long long)E << chunks_log2;
    if (idx >= total) return;
    int chunks = 1 << chunks_log2;
    int e = (int)(idx >> chunks_log2);
    int c = (int)(idx & (chunks - 1));
    int s = ei[e];
    int d = ei[E + e];
    float4 v = x[(long long)s * chunks + c];
    float* a = agg + (((long long)d << chunks_log2) + c) * 4;
    atomicAdd(a + 0, v.x);
    atomicAdd(a + 1, v.y);
    atomicAdd(a + 2, v.z);
    atomicAdd(a + 3, v.w);
}

// ---------------- h = (1+eps)*x + agg (in-place into agg) ----------------
__global__ __launch_bounds__(256) void combine_kernel(
    const float4* __restrict__ x, float4* __restrict__ agg,
    const float* __restrict__ eps_ptr, long long total4)
{
    long long i = (long long)blockIdx.x * blockDim.x + threadIdx.x;
    if (i >= total4) return;
    float e1 = 1.0f + (eps_ptr ? *eps_ptr : 0.0f);
    float4 xv = x[i];
    float4 av = agg[i];
    av.x = fmaf(e1, xv.x, av.x);
    av.y = fmaf(e1, xv.y, av.y);
    av.z = fmaf(e1, xv.z, av.z);
    av.w = fmaf(e1, xv.w, av.w);
    agg[i] = av;
}

__device__ inline float4 ld4(const float* p) { return *reinterpret_cast<const float4*>(p); }

// ---------------- fp32 tiled GEMM with fused epilogue ----------------
// C[M,NC] = A[M,K] @ W[K,NC]  (+bias, then FUSE: 0=ReLU, 1=BN+LeakyReLU, 2=none)
// 64x64 tile per 256-thread block, 4x4 per thread, TK=32.
// As stride 65: A-stage stores 2-way (free, m136); inner reads broadcast.
// Ws unpadded: float4 stores/reads are 2-way (free).
template <int K, int NC, int FUSE>
__global__ __launch_bounds__(256) void gemm_fused(
    const float* __restrict__ A, const float* __restrict__ W,
    const float* __restrict__ bias,
    const float* __restrict__ bn_g, const float* __restrict__ bn_b,
    const float* __restrict__ bn_m, const float* __restrict__ bn_v,
    float* __restrict__ C, int M)
{
    __shared__ float As[32][65];
    __shared__ float Ws[32][64];

    int tid = threadIdx.x;
    int m0 = blockIdx.x * 64;
    int n0 = blockIdx.y * 64;
    int ty = tid >> 4, tx = tid & 15;
    int ty4 = ty * 4, tx4 = tx * 4;

    float acc[4][4] = {};

    for (int k0 = 0; k0 < K; k0 += 32) {
        // ---- stage A tile: 64 rows x 32 k ----
        {
            int kq = tid & 7;       // float4 index along k
            int mb = tid >> 3;      // 0..31
#pragma unroll
            for (int it = 0; it < 2; ++it) {
                int m = mb + it * 32;
                int gm = m0 + m;
                float4 v = make_float4(0.f, 0.f, 0.f, 0.f);
                if (gm < M) v = ld4(A + (long long)gm * K + k0 + kq * 4);
                As[kq * 4 + 0][m] = v.x;
                As[kq * 4 + 1][m] = v.y;
                As[kq * 4 + 2][m] = v.z;
                As[kq * 4 + 3][m] = v.w;
            }
        }
        // ---- stage W tile: 32 k x 64 n ----
        {
            int nq = tid & 15;      // float4 index along n
            int kb = tid >> 4;      // 0..15
#pragma unroll
            for (int it = 0; it < 2; ++it) {
                int k = kb + it * 16;
                float4 v = ld4(W + (long long)(k0 + k) * NC + n0 + nq * 4);
                *reinterpret_cast<float4*>(&Ws[k][nq * 4]) = v;
            }
        }
        __syncthreads();
#pragma unroll
        for (int kk = 0; kk < 32; ++kk) {
            float a0 = As[kk][ty4 + 0];
            float a1 = As[kk][ty4 + 1];
            float a2 = As[kk][ty4 + 2];
            float a3 = As[kk][ty4 + 3];
            float4 b = *reinterpret_cast<const float4*>(&Ws[kk][tx4]);
            acc[0][0] = fmaf(a0, b.x, acc[0][0]);
            acc[0][1] = fmaf(a0, b.y, acc[0][1]);
            acc[0][2] = fmaf(a0, b.z, acc[0][2]);
            acc[0][3] = fmaf(a0, b.w, acc[0][3]);
            acc[1][0] = fmaf(a1, b.x, acc[1][0]);
            acc[1][1] = fmaf(a1, b.y, acc[1][1]);
            acc[1][2] = fmaf(a1, b.z, acc[1][2]);
            acc[1][3] = fmaf(a1, b.w, acc[1][3]);
            acc[2][0] = fmaf(a2, b.x, acc[2][0]);
            acc[2][1] = fmaf(a2, b.y, acc[2][1]);
            acc[2][2] = fmaf(a2, b.z, acc[2][2]);
            acc[2][3] = fmaf(a2, b.w, acc[2][3]);
            acc[3][0] = fmaf(a3, b.x, acc[3][0]);
            acc[3][1] = fmaf(a3, b.y, acc[3][1]);
            acc[3][2] = fmaf(a3, b.z, acc[3][2]);
            acc[3][3] = fmaf(a3, b.w, acc[3][3]);
        }
        __syncthreads();
    }

    // ---- epilogue ----
    int nc = n0 + tx4;
    float4 bv = ld4(bias + nc);
    float4 s4 = make_float4(0.f, 0.f, 0.f, 0.f);
    float4 t4 = make_float4(0.f, 0.f, 0.f, 0.f);
    if (FUSE == 1) {
        float4 g = ld4(bn_g + nc), bb = ld4(bn_b + nc);
        float4 mm = ld4(bn_m + nc), vv = ld4(bn_v + nc);
        s4.x = g.x * rsqrtf(vv.x + 1e-5f);
        s4.y = g.y * rsqrtf(vv.y + 1e-5f);
        s4.z = g.z * rsqrtf(vv.z + 1e-5f);
        s4.w = g.w * rsqrtf(vv.w + 1e-5f);
        t4.x = bb.x - mm.x * s4.x;
        t4.y = bb.y - mm.y * s4.y;
        t4.z = bb.z - mm.z * s4.z;
        t4.w = bb.w - mm.w * s4.w;
    }
#pragma unroll
    for (int i = 0; i < 4; ++i) {
        int gm = m0 + ty4 + i;
        if (gm >= M) break;
        float4 v;
        v.x = acc[i][0] + bv.x;
        v.y = acc[i][1] + bv.y;
        v.z = acc[i][2] + bv.z;
        v.w = acc[i][3] + bv.w;
        if (FUSE == 0) {
            v.x = fmaxf(v.x, 0.f); v.y = fmaxf(v.y, 0.f);
            v.z = fmaxf(v.z, 0.f); v.w = fmaxf(v.w, 0.f);
        } else if (FUSE == 1) {
            v.x = fmaf(v.x, s4.x, t4.x);
            v.y = fmaf(v.y, s4.y, t4.y);
            v.z = fmaf(v.z, s4.z, t4.z);
            v.w = fmaf(v.w, s4.w, t4.w);
            v.x = v.x >= 0.f ? v.x : 0.01f * v.x;
            v.y = v.y >= 0.f ? v.y : 0.01f * v.y;
            v.z = v.z >= 0.f ? v.z : 0.01f * v.z;
            v.w = v.w >= 0.f ? v.w : 0.01f * v.w;
        }
        *reinterpret_cast<float4*>(C + (long long)gm * NC + nc) = v;
    }
}

extern "C" void kernel_launch(void* const* d_in, const int* in_sizes, int n_in,
                              void* d_out, int out_size, void* d_ws, size_t ws_size,
                              hipStream_t stream)
{
    const float* x    = (const float*)d_in[0];
    const int*   ei   = (const int*)d_in[1];     // int32 on device: [src(E), dst(E)]
    const float* eps0 = (const float*)d_in[2];
    const float* W01  = (const float*)d_in[3];
    const float* b01  = (const float*)d_in[4];
    const float* W02  = (const float*)d_in[5];
    const float* b02  = (const float*)d_in[6];
    const float* W11  = (const float*)d_in[7];
    const float* b11  = (const float*)d_in[8];
    const float* W12  = (const float*)d_in[9];
    const float* b12  = (const float*)d_in[10];
    const float* eps2 = (const float*)d_in[11];
    const float* W21  = (const float*)d_in[12];
    const float* b21  = (const float*)d_in[13];
    const float* W22  = (const float*)d_in[14];
    const float* b22  = (const float*)d_in[15];
    const float* bn_g = (const float*)d_in[16];
    const float* bn_b = (const float*)d_in[17];
    const float* bn_m = (const float*)d_in[18];
    const float* bn_v = (const float*)d_in[19];

    const int Nn = in_sizes[0] / IN_F;   // 50000
    const int E  = in_sizes[1] / 2;      // 600000

    // Two ping-pong buffers of N x 256 fp32 (102.4 MB total).
    float* A = (float*)d_ws;
    float* B = A + (size_t)Nn * HID;

    dim3 blk(256);
    const int mblocks = cdiv_ll(Nn, 64);

    // ================= layer 0 (in=128) =================
    // agg(x) -> A[:,:128]; gemm A->B (ReLU); gemm B->A (BN+LReLU)
    hipMemsetAsync(A, 0, (size_t)Nn * IN_F * sizeof(float), stream);
    {
        long long tot = (long long)E * (IN_F / 4);
        scatter_add_kernel<<<cdiv_ll(tot, 256), blk, 0, stream>>>(
            (const float4*)x, ei, A, E, 5);
        long long c4 = (long long)Nn * (IN_F / 4);
        combine_kernel<<<cdiv_ll(c4, 256), blk, 0, stream>>>(
            (const float4*)x, (float4*)A, eps0, c4);
    }
    gemm_fused<128, 256, 0><<<dim3(mblocks, 4), blk, 0, stream>>>(
        A, W01, b01, nullptr, nullptr, nullptr, nullptr, B, Nn);
    gemm_fused<256, 256, 1><<<dim3(mblocks, 4), blk, 0, stream>>>(
        B, W02, b02, bn_g, bn_b, bn_m, bn_v, A, Nn);

    // ================= layer 1 =================
    // input A; agg -> B; combine -> B; gemm B->A (ReLU); gemm A->B (BN+LReLU)
    hipMemsetAsync(B, 0, (size_t)Nn * HID * sizeof(float), stream);
    {
        long long tot = (long long)E * (HID / 4);
        scatter_add_kernel<<<cdiv_ll(tot, 256), blk, 0, stream>>>(
            (const float4*)A, ei, B, E, 6);
        long long c4 = (long long)Nn * (HID / 4);
        combine_kernel<<<cdiv_ll(c4, 256), blk, 0, stream>>>(
            (const float4*)A, (float4*)B, nullptr, c4);
    }
    gemm_fused<256, 256, 0><<<dim3(mblocks, 4), blk, 0, stream>>>(
        B, W11, b11, nullptr, nullptr, nullptr, nullptr, A, Nn);
    gemm_fused<256, 256, 1><<<dim3(mblocks, 4), blk, 0, stream>>>(
        A, W12, b12, bn_g, bn_b, bn_m, bn_v, B, Nn);

    // ================= layer 2 (out=64) =================
    // input B; agg -> A; combine -> A; gemm A->B (ReLU); gemm B->d_out
    hipMemsetAsync(A, 0, (size_t)Nn * HID * sizeof(float), stream);
    {
        long long tot = (long long)E * (HID / 4);
        scatter_add_kernel<<<cdiv_ll(tot, 256), blk, 0, stream>>>(
            (const float4*)B, ei, A, E, 6);
        long long c4 = (long long)Nn * (HID / 4);
        combine_kernel<<<cdiv_ll(c4, 256), blk, 0, stream>>>(
            (const float4*)B, (float4*)A, eps2, c4);
    }
    gemm_fused<256, 256, 0><<<dim3(mblocks, 4), blk, 0, stream>>>(
        A, W21, b21, nullptr, nullptr, nullptr, nullptr, B, Nn);
    gemm_fused<256, 64, 2><<<dim3(mblocks, 1), blk, 0, stream>>>(
        B, W22, b22, nullptr, nullptr, nullptr, nullptr, (float*)d_out, Nn);
}

// Round 3
// 862.924 us; speedup vs baseline: 6.4497x; 6.4497x over previous
//
#include <hip/hip_runtime.h>

constexpr int IN_F = 128;
constexpr int HID  = 256;
constexpr int OUT_F = 64;

static inline int cdiv_ll(long long a, long long b) { return (int)((a + b - 1) / b); }

// ================= CSR build =================
__global__ __launch_bounds__(256) void deg_count_kernel(
    const int* __restrict__ ei, int* __restrict__ deg, int E)
{
    int e = blockIdx.x * blockDim.x + threadIdx.x;
    if (e >= E) return;
    atomicAdd(&deg[ei[E + e]], 1);
}

// Single-block exclusive scan over deg[0..Nn) -> row_ptr, cursor (both get the
// exclusive prefix); row_ptr[Nn] = E. 1024 threads, Hillis-Steele per 1024-chunk.
__global__ __launch_bounds__(1024) void scan_kernel(
    const int* __restrict__ deg, int* __restrict__ row_ptr,
    int* __restrict__ cursor, int Nn, int E)
{
    __shared__ int buf[1024];
    int tid = threadIdx.x;
    int carry = 0;  // replicated in every thread's registers
    for (int base = 0; base < Nn; base += 1024) {
        int i = base + tid;
        int v = (i < Nn) ? deg[i] : 0;
        buf[tid] = v;
        __syncthreads();
        for (int off = 1; off < 1024; off <<= 1) {
            int t = (tid >= off) ? buf[tid - off] : 0;
            __syncthreads();
            buf[tid] += t;
            __syncthreads();
        }
        int incl = buf[tid];
        int chunk_total = buf[1023];
        int out = carry + incl - v;
        if (i < Nn) { row_ptr[i] = out; cursor[i] = out; }
        carry += chunk_total;
        __syncthreads();  // protect buf before next chunk overwrites
    }
    if (tid == 0) row_ptr[Nn] = E;
}

__global__ __launch_bounds__(256) void csr_fill_kernel(
    const int* __restrict__ ei, int* __restrict__ cursor,
    int* __restrict__ csr_src, int E)
{
    int e = blockIdx.x * blockDim.x + threadIdx.x;
    if (e >= E) return;
    int d = ei[E + e];
    int pos = atomicAdd(&cursor[d], 1);
    csr_src[pos] = ei[e];
}

// ================= gather aggregation (fused combine) =================
// out[n] = (1+eps)*x[n] + sum_{s in in-edges(n)} x[s]
// One wave per node; lane owns a contiguous vector chunk. D=256: float4.
__global__ __launch_bounds__(256) void agg256_kernel(
    const float4* __restrict__ x4, const int* __restrict__ row_ptr,
    const int* __restrict__ csr_src, const float* __restrict__ eps_ptr,
    float4* __restrict__ out4, int Nn)
{
    int n = blockIdx.x * 4 + (threadIdx.x >> 6);
    if (n >= Nn) return;
    int lane = threadIdx.x & 63;
    size_t off = (size_t)n * 64 + lane;
    float e1 = 1.0f + (eps_ptr ? *eps_ptr : 0.0f);
    float4 xv = x4[off];
    float4 acc = make_float4(e1 * xv.x, e1 * xv.y, e1 * xv.z, e1 * xv.w);
    int beg = row_ptr[n], end = row_ptr[n + 1];
    int j = beg;
    for (; j + 1 < end; j += 2) {
        int s0 = csr_src[j], s1 = csr_src[j + 1];
        float4 v0 = x4[(size_t)s0 * 64 + lane];
        float4 v1 = x4[(size_t)s1 * 64 + lane];
        acc.x += v0.x + v1.x;
        acc.y += v0.y + v1.y;
        acc.z += v0.z + v1.z;
        acc.w += v0.w + v1.w;
    }
    if (j < end) {
        int s = csr_src[j];
        float4 v = x4[(size_t)s * 64 + lane];
        acc.x += v.x; acc.y += v.y; acc.z += v.z; acc.w += v.w;
    }
    out4[off] = acc;
}

// D=128: float2 per lane.
__global__ __launch_bounds__(256) void agg128_kernel(
    const float2* __restrict__ x2, const int* __restrict__ row_ptr,
    const int* __restrict__ csr_src, const float* __restrict__ eps_ptr,
    float2* __restrict__ out2, int Nn)
{
    int n = blockIdx.x * 4 + (threadIdx.x >> 6);
    if (n >= Nn) return;
    int lane = threadIdx.x & 63;
    size_t off = (size_t)n * 64 + lane;
    float e1 = 1.0f + (eps_ptr ? *eps_ptr : 0.0f);
    float2 xv = x2[off];
    float2 acc = make_float2(e1 * xv.x, e1 * xv.y);
    int beg = row_ptr[n], end = row_ptr[n + 1];
    int j = beg;
    for (; j + 1 < end; j += 2) {
        int s0 = csr_src[j], s1 = csr_src[j + 1];
        float2 v0 = x2[(size_t)s0 * 64 + lane];
        float2 v1 = x2[(size_t)s1 * 64 + lane];
        acc.x += v0.x + v1.x;
        acc.y += v0.y + v1.y;
    }
    if (j < end) {
        int s = csr_src[j];
        float2 v = x2[(size_t)s * 64 + lane];
        acc.x += v.x; acc.y += v.y;
    }
    out2[off] = acc;
}

__device__ inline float4 ld4(const float* p) { return *reinterpret_cast<const float4*>(p); }

// ================= fp32 tiled GEMM with fused epilogue =================
// C[M,NC] = A[M,K] @ W[K,NC]  (+bias, FUSE: 0=ReLU, 1=BN+LeakyReLU, 2=none)
template <int K, int NC, int FUSE>
__global__ __launch_bounds__(256) void gemm_fused(
    const float* __restrict__ A, const float* __restrict__ W,
    const float* __restrict__ bias,
    const float* __restrict__ bn_g, const float* __restrict__ bn_b,
    const float* __restrict__ bn_m, const float* __restrict__ bn_v,
    float* __restrict__ C, int M)
{
    __shared__ float As[32][65];
    __shared__ float Ws[32][64];

    int tid = threadIdx.x;
    int m0 = blockIdx.x * 64;
    int n0 = blockIdx.y * 64;
    int ty = tid >> 4, tx = tid & 15;
    int ty4 = ty * 4, tx4 = tx * 4;

    float acc[4][4] = {};

    for (int k0 = 0; k0 < K; k0 += 32) {
        {
            int kq = tid & 7;
            int mb = tid >> 3;
#pragma unroll
            for (int it = 0; it < 2; ++it) {
                int m = mb + it * 32;
                int gm = m0 + m;
                float4 v = make_float4(0.f, 0.f, 0.f, 0.f);
                if (gm < M) v = ld4(A + (long long)gm * K + k0 + kq * 4);
                As[kq * 4 + 0][m] = v.x;
                As[kq * 4 + 1][m] = v.y;
                As[kq * 4 + 2][m] = v.z;
                As[kq * 4 + 3][m] = v.w;
            }
        }
        {
            int nq = tid & 15;
            int kb = tid >> 4;
#pragma unroll
            for (int it = 0; it < 2; ++it) {
                int k = kb + it * 16;
                float4 v = ld4(W + (long long)(k0 + k) * NC + n0 + nq * 4);
                *reinterpret_cast<float4*>(&Ws[k][nq * 4]) = v;
            }
        }
        __syncthreads();
#pragma unroll
        for (int kk = 0; kk < 32; ++kk) {
            float a0 = As[kk][ty4 + 0];
            float a1 = As[kk][ty4 + 1];
            float a2 = As[kk][ty4 + 2];
            float a3 = As[kk][ty4 + 3];
            float4 b = *reinterpret_cast<const float4*>(&Ws[kk][tx4]);
            acc[0][0] = fmaf(a0, b.x, acc[0][0]);
            acc[0][1] = fmaf(a0, b.y, acc[0][1]);
            acc[0][2] = fmaf(a0, b.z, acc[0][2]);
            acc[0][3] = fmaf(a0, b.w, acc[0][3]);
            acc[1][0] = fmaf(a1, b.x, acc[1][0]);
            acc[1][1] = fmaf(a1, b.y, acc[1][1]);
            acc[1][2] = fmaf(a1, b.z, acc[1][2]);
            acc[1][3] = fmaf(a1, b.w, acc[1][3]);
            acc[2][0] = fmaf(a2, b.x, acc[2][0]);
            acc[2][1] = fmaf(a2, b.y, acc[2][1]);
            acc[2][2] = fmaf(a2, b.z, acc[2][2]);
            acc[2][3] = fmaf(a2, b.w, acc[2][3]);
            acc[3][0] = fmaf(a3, b.x, acc[3][0]);
            acc[3][1] = fmaf(a3, b.y, acc[3][1]);
            acc[3][2] = fmaf(a3, b.z, acc[3][2]);
            acc[3][3] = fmaf(a3, b.w, acc[3][3]);
        }
        __syncthreads();
    }

    int nc = n0 + tx4;
    float4 bv = ld4(bias + nc);
    float4 s4 = make_float4(0.f, 0.f, 0.f, 0.f);
    float4 t4 = make_float4(0.f, 0.f, 0.f, 0.f);
    if (FUSE == 1) {
        float4 g = ld4(bn_g + nc), bb = ld4(bn_b + nc);
        float4 mm = ld4(bn_m + nc), vv = ld4(bn_v + nc);
        s4.x = g.x * rsqrtf(vv.x + 1e-5f);
        s4.y = g.y * rsqrtf(vv.y + 1e-5f);
        s4.z = g.z * rsqrtf(vv.z + 1e-5f);
        s4.w = g.w * rsqrtf(vv.w + 1e-5f);
        t4.x = bb.x - mm.x * s4.x;
        t4.y = bb.y - mm.y * s4.y;
        t4.z = bb.z - mm.z * s4.z;
        t4.w = bb.w - mm.w * s4.w;
    }
#pragma unroll
    for (int i = 0; i < 4; ++i) {
        int gm = m0 + ty4 + i;
        if (gm >= M) break;
        float4 v;
        v.x = acc[i][0] + bv.x;
        v.y = acc[i][1] + bv.y;
        v.z = acc[i][2] + bv.z;
        v.w = acc[i][3] + bv.w;
        if (FUSE == 0) {
            v.x = fmaxf(v.x, 0.f); v.y = fmaxf(v.y, 0.f);
            v.z = fmaxf(v.z, 0.f); v.w = fmaxf(v.w, 0.f);
        } else if (FUSE == 1) {
            v.x = fmaf(v.x, s4.x, t4.x);
            v.y = fmaf(v.y, s4.y, t4.y);
            v.z = fmaf(v.z, s4.z, t4.z);
            v.w = fmaf(v.w, s4.w, t4.w);
            v.x = v.x >= 0.f ? v.x : 0.01f * v.x;
            v.y = v.y >= 0.f ? v.y : 0.01f * v.y;
            v.z = v.z >= 0.f ? v.z : 0.01f * v.z;
            v.w = v.w >= 0.f ? v.w : 0.01f * v.w;
        }
        *reinterpret_cast<float4*>(C + (long long)gm * NC + nc) = v;
    }
}

extern "C" void kernel_launch(void* const* d_in, const int* in_sizes, int n_in,
                              void* d_out, int out_size, void* d_ws, size_t ws_size,
                              hipStream_t stream)
{
    const float* x    = (const float*)d_in[0];
    const int*   ei   = (const int*)d_in[1];     // int32: [src(E), dst(E)]
    const float* eps0 = (const float*)d_in[2];
    const float* W01  = (const float*)d_in[3];
    const float* b01  = (const float*)d_in[4];
    const float* W02  = (const float*)d_in[5];
    const float* b02  = (const float*)d_in[6];
    const float* W11  = (const float*)d_in[7];
    const float* b11  = (const float*)d_in[8];
    const float* W12  = (const float*)d_in[9];
    const float* b12  = (const float*)d_in[10];
    const float* eps2 = (const float*)d_in[11];
    const float* W21  = (const float*)d_in[12];
    const float* b21  = (const float*)d_in[13];
    const float* W22  = (const float*)d_in[14];
    const float* b22  = (const float*)d_in[15];
    const float* bn_g = (const float*)d_in[16];
    const float* bn_b = (const float*)d_in[17];
    const float* bn_m = (const float*)d_in[18];
    const float* bn_v = (const float*)d_in[19];

    const int Nn = in_sizes[0] / IN_F;   // 50000
    const int E  = in_sizes[1] / 2;      // 600000

    // Workspace: A,B ping-pong (N x 256 f32) + CSR ints (~2.8 MB)
    float* A = (float*)d_ws;
    float* B = A + (size_t)Nn * HID;
    int* row_ptr = (int*)(B + (size_t)Nn * HID);
    int* cursor  = row_ptr + (Nn + 1);
    int* deg     = cursor + Nn;
    int* csr_src = deg + Nn;

    dim3 blk(256);
    const int mblocks = cdiv_ll(Nn, 64);
    const int nblocks = cdiv_ll(Nn, 4);

    // ---- CSR build (by dst) ----
    hipMemsetAsync(deg, 0, (size_t)Nn * sizeof(int), stream);
    deg_count_kernel<<<cdiv_ll(E, 256), blk, 0, stream>>>(ei, deg, E);
    scan_kernel<<<1, 1024, 0, stream>>>(deg, row_ptr, cursor, Nn, E);
    csr_fill_kernel<<<cdiv_ll(E, 256), blk, 0, stream>>>(ei, cursor, csr_src, E);

    // ================= layer 0 (in=128) =================
    agg128_kernel<<<nblocks, blk, 0, stream>>>(
        (const float2*)x, row_ptr, csr_src, eps0, (float2*)A, Nn);
    gemm_fused<128, 256, 0><<<dim3(mblocks, 4), blk, 0, stream>>>(
        A, W01, b01, nullptr, nullptr, nullptr, nullptr, B, Nn);
    gemm_fused<256, 256, 1><<<dim3(mblocks, 4), blk, 0, stream>>>(
        B, W02, b02, bn_g, bn_b, bn_m, bn_v, A, Nn);

    // ================= layer 1 =================
    agg256_kernel<<<nblocks, blk, 0, stream>>>(
        (const float4*)A, row_ptr, csr_src, nullptr, (float4*)B, Nn);
    gemm_fused<256, 256, 0><<<dim3(mblocks, 4), blk, 0, stream>>>(
        B, W11, b11, nullptr, nullptr, nullptr, nullptr, A, Nn);
    gemm_fused<256, 256, 1><<<dim3(mblocks, 4), blk, 0, stream>>>(
        A, W12, b12, bn_g, bn_b, bn_m, bn_v, B, Nn);

    // ================= layer 2 (out=64) =================
    agg256_kernel<<<nblocks, blk, 0, stream>>>(
        (const float4*)B, row_ptr, csr_src, eps2, (float4*)A, Nn);
    gemm_fused<256, 256, 0><<<dim3(mblocks, 4), blk, 0, stream>>>(
        A, W21, b21, nullptr, nullptr, nullptr, nullptr, B, Nn);
    gemm_fused<256, 64, 2><<<dim3(mblocks, 1), blk, 0, stream>>>(
        B, W22, b22, nullptr, nullptr, nullptr, nullptr, (float*)d_out, Nn);
}

// Round 4
// 497.541 us; speedup vs baseline: 11.1862x; 1.7344x over previous
//
#include <hip/hip_runtime.h>

typedef unsigned short u16;
typedef unsigned int u32;

constexpr int IN_F = 128;
constexpr int HID  = 256;
constexpr int OUT_F = 64;

static inline int cdiv_i(long long a, long long b) { return (int)((a + b - 1) / b); }

__device__ inline float b2f(u16 h) { return __uint_as_float(((u32)h) << 16); }
__device__ inline u16 f2b(float f) {
    u32 u = __float_as_uint(f);
    u32 r = (u + 0x7FFFu + ((u >> 16) & 1u)) >> 16;   // RNE
    return (u16)r;
}

// ================= CSR build =================
__global__ __launch_bounds__(256) void deg_count_kernel(
    const int* __restrict__ ei, int* __restrict__ deg, int E)
{
    int e = blockIdx.x * blockDim.x + threadIdx.x;
    if (e >= E) return;
    atomicAdd(&deg[ei[E + e]], 1);
}

__global__ __launch_bounds__(1024) void scan_kernel(
    const int* __restrict__ deg, int* __restrict__ row_ptr,
    int* __restrict__ cursor, int Nn, int E)
{
    __shared__ int buf[1024];
    int tid = threadIdx.x;
    int carry = 0;
    for (int base = 0; base < Nn; base += 1024) {
        int i = base + tid;
        int v = (i < Nn) ? deg[i] : 0;
        buf[tid] = v;
        __syncthreads();
        for (int off = 1; off < 1024; off <<= 1) {
            int t = (tid >= off) ? buf[tid - off] : 0;
            __syncthreads();
            buf[tid] += t;
            __syncthreads();
        }
        int incl = buf[tid];
        int chunk_total = buf[1023];
        int out = carry + incl - v;
        if (i < Nn) { row_ptr[i] = out; cursor[i] = out; }
        carry += chunk_total;
        __syncthreads();
    }
    if (tid == 0) row_ptr[Nn] = E;
}

__global__ __launch_bounds__(256) void csr_fill_kernel(
    const int* __restrict__ ei, int* __restrict__ cursor,
    int* __restrict__ csr_src, int E)
{
    int e = blockIdx.x * blockDim.x + threadIdx.x;
    if (e >= E) return;
    int d = ei[E + e];
    int pos = atomicAdd(&cursor[d], 1);
    csr_src[pos] = ei[e];
}

// ================= conversions =================
// x fp32 -> bf16 (vectorized)
__global__ __launch_bounds__(256) void xconv_kernel(
    const float4* __restrict__ in, ushort4* __restrict__ out, long long total4)
{
    long long i = (long long)blockIdx.x * blockDim.x + threadIdx.x;
    if (i >= total4) return;
    float4 v = in[i];
    ushort4 o;
    o.x = f2b(v.x); o.y = f2b(v.y); o.z = f2b(v.z); o.w = f2b(v.w);
    out[i] = o;
}

// W fp32 [K][NC] -> Wt bf16 [NC][K];  K = 1<<kshift
__global__ __launch_bounds__(256) void wconv_kernel(
    const float* __restrict__ W, u16* __restrict__ Wt, int kshift, int NC)
{
    int K = 1 << kshift;
    int id = blockIdx.x * blockDim.x + threadIdx.x;
    if (id >= K * NC) return;
    int n = id >> kshift;
    int k = id & (K - 1);
    Wt[id] = f2b(W[(long long)k * NC + n]);
}

// ================= gather aggregation (bf16 in/out, fp32 accum) =================
// D=256: lane owns ushort4 (4 bf16); one wave per node.
__global__ __launch_bounds__(256) void agg256_bf16(
    const ushort4* __restrict__ x, const int* __restrict__ row_ptr,
    const int* __restrict__ csr_src, const float* __restrict__ eps_ptr,
    ushort4* __restrict__ out, int Nn)
{
    int n = blockIdx.x * 4 + (threadIdx.x >> 6);
    if (n >= Nn) return;
    int lane = threadIdx.x & 63;
    size_t off = (size_t)n * 64 + lane;
    float e1 = 1.0f + (eps_ptr ? *eps_ptr : 0.0f);
    ushort4 xv = x[off];
    float a0 = e1 * b2f(xv.x), a1 = e1 * b2f(xv.y);
    float a2 = e1 * b2f(xv.z), a3 = e1 * b2f(xv.w);
    int beg = row_ptr[n], end = row_ptr[n + 1];
    int j = beg;
    for (; j + 1 < end; j += 2) {
        int s0 = csr_src[j], s1 = csr_src[j + 1];
        ushort4 v0 = x[(size_t)s0 * 64 + lane];
        ushort4 v1 = x[(size_t)s1 * 64 + lane];
        a0 += b2f(v0.x) + b2f(v1.x);
        a1 += b2f(v0.y) + b2f(v1.y);
        a2 += b2f(v0.z) + b2f(v1.z);
        a3 += b2f(v0.w) + b2f(v1.w);
    }
    if (j < end) {
        int s = csr_src[j];
        ushort4 v = x[(size_t)s * 64 + lane];
        a0 += b2f(v.x); a1 += b2f(v.y); a2 += b2f(v.z); a3 += b2f(v.w);
    }
    ushort4 o;
    o.x = f2b(a0); o.y = f2b(a1); o.z = f2b(a2); o.w = f2b(a3);
    out[off] = o;
}

// D=128: lane owns a dword (2 bf16).
__global__ __launch_bounds__(256) void agg128_bf16(
    const u32* __restrict__ x, const int* __restrict__ row_ptr,
    const int* __restrict__ csr_src, const float* __restrict__ eps_ptr,
    u32* __restrict__ out, int Nn)
{
    int n = blockIdx.x * 4 + (threadIdx.x >> 6);
    if (n >= Nn) return;
    int lane = threadIdx.x & 63;
    size_t off = (size_t)n * 64 + lane;
    float e1 = 1.0f + (eps_ptr ? *eps_ptr : 0.0f);
    u32 xv = x[off];
    float a0 = e1 * b2f((u16)(xv & 0xffff));
    float a1 = e1 * b2f((u16)(xv >> 16));
    int beg = row_ptr[n], end = row_ptr[n + 1];
    int j = beg;
    for (; j + 1 < end; j += 2) {
        u32 v0 = x[(size_t)csr_src[j] * 64 + lane];
        u32 v1 = x[(size_t)csr_src[j + 1] * 64 + lane];
        a0 += b2f((u16)(v0 & 0xffff)) + b2f((u16)(v1 & 0xffff));
        a1 += b2f((u16)(v0 >> 16)) + b2f((u16)(v1 >> 16));
    }
    if (j < end) {
        u32 v = x[(size_t)csr_src[j] * 64 + lane];
        a0 += b2f((u16)(v & 0xffff));
        a1 += b2f((u16)(v >> 16));
    }
    out[off] = ((u32)f2b(a1) << 16) | (u32)f2b(a0);
}

// ================= bf16 MFMA GEMM =================
// C[M,NC] = A[M,K](bf16) @ Wt[NC,K](bf16)^T  (+bias; FUSE 0=ReLU,1=BN+LReLU,2=none)
// Block: 256 thr = 4 waves in WM x WN grid; each wave owns a 64x64 sub-tile
// (4x4 fragments of 16x16x32). BK=64. LDS tiles [rows][64] bf16, 128B/row,
// XOR-swizzled in 16B granules: granule cb at (row, cb^(row&7)).
// Staged via global_load_lds(16B): linear LDS dest + inverse-swizzled global src.
using bf16x8 = __attribute__((ext_vector_type(8))) short;
using f32x4  = __attribute__((ext_vector_type(4))) float;

__device__ inline void gload_lds16(const void* g, void* l) {
    __builtin_amdgcn_global_load_lds(
        (const __attribute__((address_space(1))) u32*)g,
        (__attribute__((address_space(3))) u32*)l, 16, 0, 0);
}

template <int K, int BM, int BN, int WM, int WN, int FUSE, bool OUT_F32>
__global__ __launch_bounds__(256) void gemm_mfma(
    const u16* __restrict__ A, const u16* __restrict__ Wt,
    const float* __restrict__ bias,
    const float* __restrict__ bn_g, const float* __restrict__ bn_b,
    const float* __restrict__ bn_m, const float* __restrict__ bn_v,
    void* __restrict__ Cout, int M, int NC)
{
    __shared__ u16 As[BM * 64];
    __shared__ u16 Bs[BN * 64];

    const int tid = threadIdx.x;
    const int wave = tid >> 6;
    const int lane = tid & 63;
    const int wm = wave / WN;
    const int wn = wave % WN;
    const int m0 = blockIdx.x * BM;
    const int n0 = blockIdx.y * BN;
    const int l15 = lane & 15;
    const int l4  = lane >> 4;

    f32x4 acc[4][4] = {};

    for (int k0 = 0; k0 < K; k0 += 64) {
        // ---- stage A: BM rows x 64 k (granule = 16B = 8 bf16) ----
        constexpr int AIW = (BM / 8) / 4;   // instrs per wave
#pragma unroll
        for (int i = 0; i < AIW; ++i) {
            int inst = wave * AIW + i;
            int g = inst * 64 + lane;
            int row = g >> 3;
            int cb = (g & 7) ^ (row & 7);   // inverse swizzle on source
            int grow = m0 + row;
            if (grow >= M) grow = M - 1;
            gload_lds16(A + (size_t)grow * K + k0 + cb * 8, As + inst * 512);
        }
        // ---- stage B: BN rows x 64 k ----
        constexpr int BIW = (BN / 8) / 4;
#pragma unroll
        for (int i = 0; i < BIW; ++i) {
            int inst = wave * BIW + i;
            int g = inst * 64 + lane;
            int row = g >> 3;
            int cb = (g & 7) ^ (row & 7);
            gload_lds16(Wt + (size_t)(n0 + row) * K + k0 + cb * 8, Bs + inst * 512);
        }
        __syncthreads();   // drains vmcnt before barrier

#pragma unroll
        for (int kk = 0; kk < 2; ++kk) {
            bf16x8 af[4], bf[4];
#pragma unroll
            for (int m = 0; m < 4; ++m) {
                int row = wm * 64 + m * 16 + l15;
                int cb = kk * 4 + l4;
                af[m] = *(const bf16x8*)(As + row * 64 + ((cb ^ (row & 7)) * 8));
            }
#pragma unroll
            for (int n = 0; n < 4; ++n) {
                int row = wn * 64 + n * 16 + l15;
                int cb = kk * 4 + l4;
                bf[n] = *(const bf16x8*)(Bs + row * 64 + ((cb ^ (row & 7)) * 8));
            }
#pragma unroll
            for (int m = 0; m < 4; ++m)
#pragma unroll
                for (int n = 0; n < 4; ++n)
                    acc[m][n] = __builtin_amdgcn_mfma_f32_16x16x32_bf16(
                        af[m], bf[n], acc[m][n], 0, 0, 0);
        }
        __syncthreads();
    }

    // ---- epilogue: C[row=(l>>4)*4+j][col=l&15] per fragment ----
#pragma unroll
    for (int n = 0; n < 4; ++n) {
        int col = n0 + wn * 64 + n * 16 + l15;
        float bv = bias[col];
        float sc = 1.0f, sh = 0.0f;
        if (FUSE == 1) {
            float g = bn_g[col], be = bn_b[col], mm = bn_m[col], vv = bn_v[col];
            sc = g * rsqrtf(vv + 1e-5f);
            sh = be - mm * sc;
        }
#pragma unroll
        for (int m = 0; m < 4; ++m) {
            int rb = m0 + wm * 64 + m * 16 + l4 * 4;
#pragma unroll
            for (int j = 0; j < 4; ++j) {
                int gm = rb + j;
                if (gm >= M) continue;
                float v = acc[m][n][j] + bv;
                if (FUSE == 0) v = fmaxf(v, 0.0f);
                else if (FUSE == 1) {
                    v = fmaf(v, sc, sh);
                    v = v >= 0.0f ? v : 0.01f * v;
                }
                if (OUT_F32) ((float*)Cout)[(size_t)gm * NC + col] = v;
                else         ((u16*)Cout)[(size_t)gm * NC + col] = f2b(v);
            }
        }
    }
}

extern "C" void kernel_launch(void* const* d_in, const int* in_sizes, int n_in,
                              void* d_out, int out_size, void* d_ws, size_t ws_size,
                              hipStream_t stream)
{
    const float* x    = (const float*)d_in[0];
    const int*   ei   = (const int*)d_in[1];     // int32: [src(E), dst(E)]
    const float* eps0 = (const float*)d_in[2];
    const float* W01  = (const float*)d_in[3];
    const float* b01  = (const float*)d_in[4];
    const float* W02  = (const float*)d_in[5];
    const float* b02  = (const float*)d_in[6];
    const float* W11  = (const float*)d_in[7];
    const float* b11  = (const float*)d_in[8];
    const float* W12  = (const float*)d_in[9];
    const float* b12  = (const float*)d_in[10];
    const float* eps2 = (const float*)d_in[11];
    const float* W21  = (const float*)d_in[12];
    const float* b21  = (const float*)d_in[13];
    const float* W22  = (const float*)d_in[14];
    const float* b22  = (const float*)d_in[15];
    const float* bn_g = (const float*)d_in[16];
    const float* bn_b = (const float*)d_in[17];
    const float* bn_m = (const float*)d_in[18];
    const float* bn_v = (const float*)d_in[19];

    const int Nn = in_sizes[0] / IN_F;   // 50000
    const int E  = in_sizes[1] / 2;      // 600000

    // ---- workspace carve-up (bf16 activations) ----
    u16* P = (u16*)d_ws;                       // N x 256 bf16
    u16* Q = P + (size_t)Nn * HID;             // N x 256 bf16
    u16* Xb = Q + (size_t)Nn * HID;            // N x 128 bf16
    u16* Wt01 = Xb + (size_t)Nn * IN_F;        // [256][128]
    u16* Wt02 = Wt01 + HID * IN_F;             // [256][256]
    u16* Wt11 = Wt02 + HID * HID;
    u16* Wt12 = Wt11 + HID * HID;
    u16* Wt21 = Wt12 + HID * HID;
    u16* Wt22 = Wt21 + HID * HID;              // [64][256]
    int* row_ptr = (int*)(Wt22 + OUT_F * HID);
    int* cursor  = row_ptr + (Nn + 1);
    int* deg     = cursor + Nn;
    int* csr_src = deg + Nn;

    dim3 blk(256);
    const int nwave_blocks = cdiv_i(Nn, 4);

    // ---- CSR build (by dst) ----
    hipMemsetAsync(deg, 0, (size_t)Nn * sizeof(int), stream);
    deg_count_kernel<<<cdiv_i(E, 256), blk, 0, stream>>>(ei, deg, E);
    scan_kernel<<<1, 1024, 0, stream>>>(deg, row_ptr, cursor, Nn, E);
    csr_fill_kernel<<<cdiv_i(E, 256), blk, 0, stream>>>(ei, cursor, csr_src, E);

    // ---- convert x and weights to bf16 (weights transposed to [N][K]) ----
    xconv_kernel<<<cdiv_i((long long)Nn * IN_F / 4, 256), blk, 0, stream>>>(
        (const float4*)x, (ushort4*)Xb, (long long)Nn * IN_F / 4);
    wconv_kernel<<<cdiv_i(IN_F * HID, 256), blk, 0, stream>>>(W01, Wt01, 7, HID);
    wconv_kernel<<<cdiv_i(HID * HID, 256), blk, 0, stream>>>(W02, Wt02, 8, HID);
    wconv_kernel<<<cdiv_i(HID * HID, 256), blk, 0, stream>>>(W11, Wt11, 8, HID);
    wconv_kernel<<<cdiv_i(HID * HID, 256), blk, 0, stream>>>(W12, Wt12, 8, HID);
    wconv_kernel<<<cdiv_i(HID * HID, 256), blk, 0, stream>>>(W21, Wt21, 8, HID);
    wconv_kernel<<<cdiv_i(HID * OUT_F, 256), blk, 0, stream>>>(W22, Wt22, 8, OUT_F);

    const dim3 gA(cdiv_i(Nn, 128), 2);   // 128x128 tiles, NC=256
    const dim3 gF(cdiv_i(Nn, 256), 1);   // 256x64 tile, NC=64

    // ================= layer 0 (in=128) =================
    agg128_bf16<<<nwave_blocks, blk, 0, stream>>>(
        (const u32*)Xb, row_ptr, csr_src, eps0, (u32*)P, Nn);
    gemm_mfma<128, 128, 128, 2, 2, 0, false><<<gA, blk, 0, stream>>>(
        P, Wt01, b01, nullptr, nullptr, nullptr, nullptr, Q, Nn, HID);
    gemm_mfma<256, 128, 128, 2, 2, 1, false><<<gA, blk, 0, stream>>>(
        Q, Wt02, b02, bn_g, bn_b, bn_m, bn_v, P, Nn, HID);

    // ================= layer 1 =================
    agg256_bf16<<<nwave_blocks, blk, 0, stream>>>(
        (const ushort4*)P, row_ptr, csr_src, nullptr, (ushort4*)Q, Nn);
    gemm_mfma<256, 128, 128, 2, 2, 0, false><<<gA, blk, 0, stream>>>(
        Q, Wt11, b11, nullptr, nullptr, nullptr, nullptr, P, Nn, HID);
    gemm_mfma<256, 128, 128, 2, 2, 1, false><<<gA, blk, 0, stream>>>(
        P, Wt12, b12, bn_g, bn_b, bn_m, bn_v, Q, Nn, HID);

    // ================= layer 2 (out=64) =================
    agg256_bf16<<<nwave_blocks, blk, 0, stream>>>(
        (const ushort4*)Q, row_ptr, csr_src, eps2, (ushort4*)P, Nn);
    gemm_mfma<256, 128, 128, 2, 2, 0, false><<<gA, blk, 0, stream>>>(
        P, Wt21, b21, nullptr, nullptr, nullptr, nullptr, Q, Nn, HID);
    gemm_mfma<256, 256, 64, 4, 1, 2, true><<<gF, blk, 0, stream>>>(
        Q, Wt22, b22, nullptr, nullptr, nullptr, nullptr, d_out, Nn, OUT_F);
}

// Round 5
// 409.387 us; speedup vs baseline: 13.5950x; 1.2153x over previous
//
#include <hip/hip_runtime.h>

typedef unsigned short u16;
typedef unsigned int u32;

constexpr int IN_F = 128;
constexpr int HID  = 256;
constexpr int OUT_F = 64;

static inline int cdiv_i(long long a, long long b) { return (int)((a + b - 1) / b); }

__device__ inline float b2f(u16 h) { return __uint_as_float(((u32)h) << 16); }
__device__ inline u16 f2b(float f) {
    u32 u = __float_as_uint(f);
    u32 r = (u + 0x7FFFu + ((u >> 16) & 1u)) >> 16;   // RNE
    return (u16)r;
}

// ================= CSR build =================
__global__ __launch_bounds__(256) void deg_count_kernel(
    const int* __restrict__ ei, int* __restrict__ deg, int E)
{
    int e = blockIdx.x * blockDim.x + threadIdx.x;
    if (e >= E) return;
    atomicAdd(&deg[ei[E + e]], 1);
}

// --- two-level scan: (A) per-block local scan, (B) scan block sums, (C) add ---
__global__ __launch_bounds__(1024) void block_scan_kernel(
    const int* __restrict__ deg, int* __restrict__ row_ptr,
    int* __restrict__ blksum, int Nn)
{
    __shared__ int buf[1024];
    int i = blockIdx.x * 1024 + threadIdx.x;
    int v = (i < Nn) ? deg[i] : 0;
    buf[threadIdx.x] = v;
    __syncthreads();
    for (int off = 1; off < 1024; off <<= 1) {
        int t = (threadIdx.x >= off) ? buf[threadIdx.x - off] : 0;
        __syncthreads();
        buf[threadIdx.x] += t;
        __syncthreads();
    }
    if (i < Nn) row_ptr[i] = buf[threadIdx.x] - v;   // local exclusive
    if (threadIdx.x == 1023) blksum[blockIdx.x] = buf[1023];
}

__global__ __launch_bounds__(1024) void scan_blksums_kernel(
    int* __restrict__ blksum, int nblk)
{
    __shared__ int buf[1024];
    int v = (threadIdx.x < nblk) ? blksum[threadIdx.x] : 0;
    buf[threadIdx.x] = v;
    __syncthreads();
    for (int off = 1; off < 1024; off <<= 1) {
        int t = (threadIdx.x >= off) ? buf[threadIdx.x - off] : 0;
        __syncthreads();
        buf[threadIdx.x] += t;
        __syncthreads();
    }
    if (threadIdx.x < nblk) blksum[threadIdx.x] = buf[threadIdx.x] - v;  // exclusive
}

__global__ __launch_bounds__(1024) void add_offsets_kernel(
    int* __restrict__ row_ptr, int* __restrict__ cursor,
    const int* __restrict__ blksum, int Nn, int E)
{
    int i = blockIdx.x * 1024 + threadIdx.x;
    if (i < Nn) {
        int r = row_ptr[i] + blksum[i >> 10];
        row_ptr[i] = r;
        cursor[i]  = r;
    } else if (i == Nn) {
        row_ptr[Nn] = E;
    }
}

__global__ __launch_bounds__(256) void csr_fill_kernel(
    const int* __restrict__ ei, int* __restrict__ cursor,
    int* __restrict__ csr_src, int E)
{
    int e = blockIdx.x * blockDim.x + threadIdx.x;
    if (e >= E) return;
    int d = ei[E + e];
    int pos = atomicAdd(&cursor[d], 1);
    csr_src[pos] = ei[e];
}

// ================= conversions =================
__global__ __launch_bounds__(256) void xconv_kernel(
    const float4* __restrict__ in, ushort4* __restrict__ out, long long total4)
{
    long long i = (long long)blockIdx.x * blockDim.x + threadIdx.x;
    if (i >= total4) return;
    float4 v = in[i];
    ushort4 o;
    o.x = f2b(v.x); o.y = f2b(v.y); o.z = f2b(v.z); o.w = f2b(v.w);
    out[i] = o;
}

// All six weights fp32 [K][NC] -> bf16 [NC][K], one launch.
__global__ __launch_bounds__(256) void wconv_all_kernel(
    const float* __restrict__ W01, const float* __restrict__ W02,
    const float* __restrict__ W11, const float* __restrict__ W12,
    const float* __restrict__ W21, const float* __restrict__ W22,
    u16* __restrict__ Wt01, u16* __restrict__ Wt02,
    u16* __restrict__ Wt11, u16* __restrict__ Wt12,
    u16* __restrict__ Wt21, u16* __restrict__ Wt22)
{
    int id = blockIdx.x * blockDim.x + threadIdx.x;
    const float* W; u16* Wt; int kshift, NC;
    if (id < 32768)                  { W = W01; Wt = Wt01; kshift = 7; NC = 256; }
    else if ((id -= 32768) < 65536)  { W = W02; Wt = Wt02; kshift = 8; NC = 256; }
    else if ((id -= 65536) < 65536)  { W = W11; Wt = Wt11; kshift = 8; NC = 256; }
    else if ((id -= 65536) < 65536)  { W = W12; Wt = Wt12; kshift = 8; NC = 256; }
    else if ((id -= 65536) < 65536)  { W = W21; Wt = Wt21; kshift = 8; NC = 256; }
    else if ((id -= 65536) < 16384)  { W = W22; Wt = Wt22; kshift = 8; NC = 64;  }
    else return;
    int K = 1 << kshift;
    int n = id >> kshift;
    int k = id & (K - 1);
    Wt[id] = f2b(W[(long long)k * NC + n]);
}

// ================= gather aggregation (bf16 in/out, fp32 accum) =================
__global__ __launch_bounds__(256) void agg256_bf16(
    const ushort4* __restrict__ x, const int* __restrict__ row_ptr,
    const int* __restrict__ csr_src, const float* __restrict__ eps_ptr,
    ushort4* __restrict__ out, int Nn)
{
    int n = blockIdx.x * 4 + (threadIdx.x >> 6);
    if (n >= Nn) return;
    int lane = threadIdx.x & 63;
    size_t off = (size_t)n * 64 + lane;
    float e1 = 1.0f + (eps_ptr ? *eps_ptr : 0.0f);
    ushort4 xv = x[off];
    float a0 = e1 * b2f(xv.x), a1 = e1 * b2f(xv.y);
    float a2 = e1 * b2f(xv.z), a3 = e1 * b2f(xv.w);
    int beg = row_ptr[n], end = row_ptr[n + 1];
    int j = beg;
    for (; j + 1 < end; j += 2) {
        int s0 = csr_src[j], s1 = csr_src[j + 1];
        ushort4 v0 = x[(size_t)s0 * 64 + lane];
        ushort4 v1 = x[(size_t)s1 * 64 + lane];
        a0 += b2f(v0.x) + b2f(v1.x);
        a1 += b2f(v0.y) + b2f(v1.y);
        a2 += b2f(v0.z) + b2f(v1.z);
        a3 += b2f(v0.w) + b2f(v1.w);
    }
    if (j < end) {
        int s = csr_src[j];
        ushort4 v = x[(size_t)s * 64 + lane];
        a0 += b2f(v.x); a1 += b2f(v.y); a2 += b2f(v.z); a3 += b2f(v.w);
    }
    ushort4 o;
    o.x = f2b(a0); o.y = f2b(a1); o.z = f2b(a2); o.w = f2b(a3);
    out[off] = o;
}

__global__ __launch_bounds__(256) void agg128_bf16(
    const u32* __restrict__ x, const int* __restrict__ row_ptr,
    const int* __restrict__ csr_src, const float* __restrict__ eps_ptr,
    u32* __restrict__ out, int Nn)
{
    int n = blockIdx.x * 4 + (threadIdx.x >> 6);
    if (n >= Nn) return;
    int lane = threadIdx.x & 63;
    size_t off = (size_t)n * 64 + lane;
    float e1 = 1.0f + (eps_ptr ? *eps_ptr : 0.0f);
    u32 xv = x[off];
    float a0 = e1 * b2f((u16)(xv & 0xffff));
    float a1 = e1 * b2f((u16)(xv >> 16));
    int beg = row_ptr[n], end = row_ptr[n + 1];
    int j = beg;
    for (; j + 1 < end; j += 2) {
        u32 v0 = x[(size_t)csr_src[j] * 64 + lane];
        u32 v1 = x[(size_t)csr_src[j + 1] * 64 + lane];
        a0 += b2f((u16)(v0 & 0xffff)) + b2f((u16)(v1 & 0xffff));
        a1 += b2f((u16)(v0 >> 16)) + b2f((u16)(v1 >> 16));
    }
    if (j < end) {
        u32 v = x[(size_t)csr_src[j] * 64 + lane];
        a0 += b2f((u16)(v & 0xffff));
        a1 += b2f((u16)(v >> 16));
    }
    out[off] = ((u32)f2b(a1) << 16) | (u32)f2b(a0);
}

// ================= bf16 MFMA GEMM =================
// C[M,NC] = A[M,K](bf16) @ Wt[NC,K](bf16)^T  (+bias; FUSE 0=ReLU,1=BN+LReLU,2=none)
// 256 thr = 4 waves (WM x WN), each wave a 64x64 sub-tile (4x4 frags 16x16x32).
// LDS [rows][64] bf16, XOR-swizzled 16B granules: (row, cb^(row&7)).
// global_load_lds(16B): linear LDS dest + inverse-swizzled global src.
using bf16x8 = __attribute__((ext_vector_type(8))) short;
using f32x4  = __attribute__((ext_vector_type(4))) float;

__device__ inline void gload_lds16(const void* g, void* l) {
    __builtin_amdgcn_global_load_lds(
        (const __attribute__((address_space(1))) u32*)g,
        (__attribute__((address_space(3))) u32*)l, 16, 0, 0);
}

template <int K, int BM, int BN, int WM, int WN, int FUSE, bool OUT_F32>
__global__ __launch_bounds__(256) void gemm_mfma(
    const u16* __restrict__ A, const u16* __restrict__ Wt,
    const float* __restrict__ bias,
    const float* __restrict__ bn_g, const float* __restrict__ bn_b,
    const float* __restrict__ bn_m, const float* __restrict__ bn_v,
    void* __restrict__ Cout, int M, int NC)
{
    __shared__ u16 As[BM * 64];
    __shared__ u16 Bs[BN * 64];

    const int tid = threadIdx.x;
    const int wave = tid >> 6;
    const int lane = tid & 63;
    const int wm = wave / WN;
    const int wn = wave % WN;
    const int m0 = blockIdx.x * BM;
    const int n0 = blockIdx.y * BN;
    const int l15 = lane & 15;
    const int l4  = lane >> 4;

    f32x4 acc[4][4] = {};

    for (int k0 = 0; k0 < K; k0 += 64) {
        constexpr int AIW = (BM / 8) / 4;
#pragma unroll
        for (int i = 0; i < AIW; ++i) {
            int inst = wave * AIW + i;
            int g = inst * 64 + lane;
            int row = g >> 3;
            int cb = (g & 7) ^ (row & 7);
            int grow = m0 + row;
            if (grow >= M) grow = M - 1;
            gload_lds16(A + (size_t)grow * K + k0 + cb * 8, As + inst * 512);
        }
        constexpr int BIW = (BN / 8) / 4;
#pragma unroll
        for (int i = 0; i < BIW; ++i) {
            int inst = wave * BIW + i;
            int g = inst * 64 + lane;
            int row = g >> 3;
            int cb = (g & 7) ^ (row & 7);
            gload_lds16(Wt + (size_t)(n0 + row) * K + k0 + cb * 8, Bs + inst * 512);
        }
        __syncthreads();

#pragma unroll
        for (int kk = 0; kk < 2; ++kk) {
            bf16x8 af[4], bf[4];
#pragma unroll
            for (int m = 0; m < 4; ++m) {
                int row = wm * 64 + m * 16 + l15;
                int cb = kk * 4 + l4;
                af[m] = *(const bf16x8*)(As + row * 64 + ((cb ^ (row & 7)) * 8));
            }
#pragma unroll
            for (int n = 0; n < 4; ++n) {
                int row = wn * 64 + n * 16 + l15;
                int cb = kk * 4 + l4;
                bf[n] = *(const bf16x8*)(Bs + row * 64 + ((cb ^ (row & 7)) * 8));
            }
#pragma unroll
            for (int m = 0; m < 4; ++m)
#pragma unroll
                for (int n = 0; n < 4; ++n)
                    acc[m][n] = __builtin_amdgcn_mfma_f32_16x16x32_bf16(
                        af[m], bf[n], acc[m][n], 0, 0, 0);
        }
        __syncthreads();
    }

#pragma unroll
    for (int n = 0; n < 4; ++n) {
        int col = n0 + wn * 64 + n * 16 + l15;
        float bv = bias[col];
        float sc = 1.0f, sh = 0.0f;
        if (FUSE == 1) {
            float g = bn_g[col], be = bn_b[col], mm = bn_m[col], vv = bn_v[col];
            sc = g * rsqrtf(vv + 1e-5f);
            sh = be - mm * sc;
        }
#pragma unroll
        for (int m = 0; m < 4; ++m) {
            int rb = m0 + wm * 64 + m * 16 + l4 * 4;
#pragma unroll
            for (int j = 0; j < 4; ++j) {
                int gm = rb + j;
                if (gm >= M) continue;
                float v = acc[m][n][j] + bv;
                if (FUSE == 0) v = fmaxf(v, 0.0f);
                else if (FUSE == 1) {
                    v = fmaf(v, sc, sh);
                    v = v >= 0.0f ? v : 0.01f * v;
                }
                if (OUT_F32) ((float*)Cout)[(size_t)gm * NC + col] = v;
                else         ((u16*)Cout)[(size_t)gm * NC + col] = f2b(v);
            }
        }
    }
}

extern "C" void kernel_launch(void* const* d_in, const int* in_sizes, int n_in,
                              void* d_out, int out_size, void* d_ws, size_t ws_size,
                              hipStream_t stream)
{
    const float* x    = (const float*)d_in[0];
    const int*   ei   = (const int*)d_in[1];     // int32: [src(E), dst(E)]
    const float* eps0 = (const float*)d_in[2];
    const float* W01  = (const float*)d_in[3];
    const float* b01  = (const float*)d_in[4];
    const float* W02  = (const float*)d_in[5];
    const float* b02  = (const float*)d_in[6];
    const float* W11  = (const float*)d_in[7];
    const float* b11  = (const float*)d_in[8];
    const float* W12  = (const float*)d_in[9];
    const float* b12  = (const float*)d_in[10];
    const float* eps2 = (const float*)d_in[11];
    const float* W21  = (const float*)d_in[12];
    const float* b21  = (const float*)d_in[13];
    const float* W22  = (const float*)d_in[14];
    const float* b22  = (const float*)d_in[15];
    const float* bn_g = (const float*)d_in[16];
    const float* bn_b = (const float*)d_in[17];
    const float* bn_m = (const float*)d_in[18];
    const float* bn_v = (const float*)d_in[19];

    const int Nn = in_sizes[0] / IN_F;   // 50000
    const int E  = in_sizes[1] / 2;      // 600000

    // ---- workspace carve-up ----
    u16* P = (u16*)d_ws;
    u16* Q = P + (size_t)Nn * HID;
    u16* Xb = Q + (size_t)Nn * HID;
    u16* Wt01 = Xb + (size_t)Nn * IN_F;
    u16* Wt02 = Wt01 + HID * IN_F;
    u16* Wt11 = Wt02 + HID * HID;
    u16* Wt12 = Wt11 + HID * HID;
    u16* Wt21 = Wt12 + HID * HID;
    u16* Wt22 = Wt21 + HID * HID;
    int* row_ptr = (int*)(Wt22 + OUT_F * HID);
    int* cursor  = row_ptr + (Nn + 1);
    int* deg     = cursor + Nn;
    int* blksum  = deg + Nn;                 // up to 1024 block sums
    int* csr_src = blksum + 1024;

    dim3 blk(256);
    const int nwave_blocks = cdiv_i(Nn, 4);
    const int nscan = cdiv_i(Nn, 1024);

    // ---- CSR build (by dst), two-level scan ----
    hipMemsetAsync(deg, 0, (size_t)Nn * sizeof(int), stream);
    deg_count_kernel<<<cdiv_i(E, 256), blk, 0, stream>>>(ei, deg, E);
    block_scan_kernel<<<nscan, 1024, 0, stream>>>(deg, row_ptr, blksum, Nn);
    scan_blksums_kernel<<<1, 1024, 0, stream>>>(blksum, nscan);
    add_offsets_kernel<<<cdiv_i(Nn + 1, 1024), 1024, 0, stream>>>(
        row_ptr, cursor, blksum, Nn, E);
    csr_fill_kernel<<<cdiv_i(E, 256), blk, 0, stream>>>(ei, cursor, csr_src, E);

    // ---- convert x and weights to bf16 ----
    xconv_kernel<<<cdiv_i((long long)Nn * IN_F / 4, 256), blk, 0, stream>>>(
        (const float4*)x, (ushort4*)Xb, (long long)Nn * IN_F / 4);
    wconv_all_kernel<<<cdiv_i(32768 + 4 * 65536 + 16384, 256), blk, 0, stream>>>(
        W01, W02, W11, W12, W21, W22, Wt01, Wt02, Wt11, Wt12, Wt21, Wt22);

    const dim3 gA(cdiv_i(Nn, 128), 2);   // 128x128 tiles, NC=256
    const dim3 gF(cdiv_i(Nn, 256), 1);   // 256x64 tile, NC=64

    // ================= layer 0 (in=128) =================
    agg128_bf16<<<nwave_blocks, blk, 0, stream>>>(
        (const u32*)Xb, row_ptr, csr_src, eps0, (u32*)P, Nn);
    gemm_mfma<128, 128, 128, 2, 2, 0, false><<<gA, blk, 0, stream>>>(
        P, Wt01, b01, nullptr, nullptr, nullptr, nullptr, Q, Nn, HID);
    gemm_mfma<256, 128, 128, 2, 2, 1, false><<<gA, blk, 0, stream>>>(
        Q, Wt02, b02, bn_g, bn_b, bn_m, bn_v, P, Nn, HID);

    // ================= layer 1 =================
    agg256_bf16<<<nwave_blocks, blk, 0, stream>>>(
        (const ushort4*)P, row_ptr, csr_src, nullptr, (ushort4*)Q, Nn);
    gemm_mfma<256, 128, 128, 2, 2, 0, false><<<gA, blk, 0, stream>>>(
        Q, Wt11, b11, nullptr, nullptr, nullptr, nullptr, P, Nn, HID);
    gemm_mfma<256, 128, 128, 2, 2, 1, false><<<gA, blk, 0, stream>>>(
        P, Wt12, b12, bn_g, bn_b, bn_m, bn_v, Q, Nn, HID);

    // ================= layer 2 (out=64) =================
    agg256_bf16<<<nwave_blocks, blk, 0, stream>>>(
        (const ushort4*)Q, row_ptr, csr_src, eps2, (ushort4*)P, Nn);
    gemm_mfma<256, 128, 128, 2, 2, 0, false><<<gA, blk, 0, stream>>>(
        P, Wt21, b21, nullptr, nullptr, nullptr, nullptr, Q, Nn, HID);
    gemm_mfma<256, 256, 64, 4, 1, 2, true><<<gF, blk, 0, stream>>>(
        Q, Wt22, b22, nullptr, nullptr, nullptr, nullptr, d_out, Nn, OUT_F);
}

// Round 6
// 344.006 us; speedup vs baseline: 16.1788x; 1.1901x over previous
//
#include <hip/hip_runtime.h>

typedef unsigned short u16;
typedef unsigned int u32;
typedef __attribute__((ext_vector_type(8))) unsigned short u16x8;

constexpr int IN_F = 128;
constexpr int HID  = 256;
constexpr int OUT_F = 64;

static inline int cdiv_i(long long a, long long b) { return (int)((a + b - 1) / b); }

__device__ inline float b2f(u16 h) { return __uint_as_float(((u32)h) << 16); }
__device__ inline u16 f2b(float f) {
    u32 u = __float_as_uint(f);
    u32 r = (u + 0x7FFFu + ((u >> 16) & 1u)) >> 16;   // RNE
    return (u16)r;
}

// ================= CSR build =================
__global__ __launch_bounds__(256) void deg_count_kernel(
    const int* __restrict__ ei, int* __restrict__ deg, int E)
{
    int e = blockIdx.x * blockDim.x + threadIdx.x;
    if (e >= E) return;
    atomicAdd(&deg[ei[E + e]], 1);
}

__global__ __launch_bounds__(1024) void block_scan_kernel(
    const int* __restrict__ deg, int* __restrict__ row_ptr,
    int* __restrict__ blksum, int Nn)
{
    __shared__ int buf[1024];
    int i = blockIdx.x * 1024 + threadIdx.x;
    int v = (i < Nn) ? deg[i] : 0;
    buf[threadIdx.x] = v;
    __syncthreads();
    for (int off = 1; off < 1024; off <<= 1) {
        int t = (threadIdx.x >= off) ? buf[threadIdx.x - off] : 0;
        __syncthreads();
        buf[threadIdx.x] += t;
        __syncthreads();
    }
    if (i < Nn) row_ptr[i] = buf[threadIdx.x] - v;   // local exclusive
    if (threadIdx.x == 1023) blksum[blockIdx.x] = buf[1023];
}

__global__ __launch_bounds__(1024) void scan_blksums_kernel(
    int* __restrict__ blksum, int nblk)
{
    __shared__ int buf[1024];
    int v = (threadIdx.x < nblk) ? blksum[threadIdx.x] : 0;
    buf[threadIdx.x] = v;
    __syncthreads();
    for (int off = 1; off < 1024; off <<= 1) {
        int t = (threadIdx.x >= off) ? buf[threadIdx.x - off] : 0;
        __syncthreads();
        buf[threadIdx.x] += t;
        __syncthreads();
    }
    if (threadIdx.x < nblk) blksum[threadIdx.x] = buf[threadIdx.x] - v;  // exclusive
}

__global__ __launch_bounds__(1024) void add_offsets_kernel(
    int* __restrict__ row_ptr, int* __restrict__ cursor,
    const int* __restrict__ blksum, int Nn, int E)
{
    int i = blockIdx.x * 1024 + threadIdx.x;
    if (i < Nn) {
        int r = row_ptr[i] + blksum[i >> 10];
        row_ptr[i] = r;
        cursor[i]  = r;
    } else if (i == Nn) {
        row_ptr[Nn] = E;
    }
}

__global__ __launch_bounds__(256) void csr_fill_kernel(
    const int* __restrict__ ei, int* __restrict__ cursor,
    int* __restrict__ csr_src, int E)
{
    int e = blockIdx.x * blockDim.x + threadIdx.x;
    if (e >= E) return;
    int d = ei[E + e];
    int pos = atomicAdd(&cursor[d], 1);
    csr_src[pos] = ei[e];
}

// ================= conversions =================
__global__ __launch_bounds__(256) void xconv_kernel(
    const float4* __restrict__ in, ushort4* __restrict__ out, long long total4)
{
    long long i = (long long)blockIdx.x * blockDim.x + threadIdx.x;
    if (i >= total4) return;
    float4 v = in[i];
    ushort4 o;
    o.x = f2b(v.x); o.y = f2b(v.y); o.z = f2b(v.z); o.w = f2b(v.w);
    out[i] = o;
}

// All six weights fp32 [K][NC] -> bf16 [NC][K], one launch.
__global__ __launch_bounds__(256) void wconv_all_kernel(
    const float* __restrict__ W01, const float* __restrict__ W02,
    const float* __restrict__ W11, const float* __restrict__ W12,
    const float* __restrict__ W21, const float* __restrict__ W22,
    u16* __restrict__ Wt01, u16* __restrict__ Wt02,
    u16* __restrict__ Wt11, u16* __restrict__ Wt12,
    u16* __restrict__ Wt21, u16* __restrict__ Wt22)
{
    int id = blockIdx.x * blockDim.x + threadIdx.x;
    const float* W; u16* Wt; int kshift, NC;
    if (id < 32768)                  { W = W01; Wt = Wt01; kshift = 7; NC = 256; }
    else if ((id -= 32768) < 65536)  { W = W02; Wt = Wt02; kshift = 8; NC = 256; }
    else if ((id -= 65536) < 65536)  { W = W11; Wt = Wt11; kshift = 8; NC = 256; }
    else if ((id -= 65536) < 65536)  { W = W12; Wt = Wt12; kshift = 8; NC = 256; }
    else if ((id -= 65536) < 65536)  { W = W21; Wt = Wt21; kshift = 8; NC = 256; }
    else if ((id -= 65536) < 16384)  { W = W22; Wt = Wt22; kshift = 8; NC = 64;  }
    else return;
    int K = 1 << kshift;
    int n = id >> kshift;
    int k = id & (K - 1);
    Wt[id] = f2b(W[(long long)k * NC + n]);
}

// ================= gather aggregation (bf16, fp32 accum) =================
// One wave per node. Lane owns a 16B (8 bf16) chunk of the row.
// D=256: 32 chunks -> 2 edge-groups of 32 lanes, each handles alternate edges.
// Cross-group shfl_xor reduce at the end; group 0 stores.
__global__ __launch_bounds__(256) void agg256_bf16(
    const u16x8* __restrict__ x, const int* __restrict__ row_ptr,
    const int* __restrict__ csr_src, const float* __restrict__ eps_ptr,
    u16x8* __restrict__ out, int Nn)
{
    int n = blockIdx.x * 4 + (threadIdx.x >> 6);
    if (n >= Nn) return;
    int lane = threadIdx.x & 63;
    int grp = lane >> 5;       // 0/1
    int sl  = lane & 31;       // chunk index
    size_t off = (size_t)n * 32 + sl;
    float acc[8];
    if (grp == 0) {
        float e1 = 1.0f + (eps_ptr ? *eps_ptr : 0.0f);
        u16x8 xv = x[off];
#pragma unroll
        for (int i = 0; i < 8; ++i) acc[i] = e1 * b2f(xv[i]);
    } else {
#pragma unroll
        for (int i = 0; i < 8; ++i) acc[i] = 0.0f;
    }
    int end = row_ptr[n + 1];
    int j = row_ptr[n] + grp;
    for (; j + 2 < end; j += 4) {           // 2 edges/group/iter
        int s0 = csr_src[j], s1 = csr_src[j + 2];
        u16x8 v0 = x[(size_t)s0 * 32 + sl];
        u16x8 v1 = x[(size_t)s1 * 32 + sl];
#pragma unroll
        for (int i = 0; i < 8; ++i) acc[i] += b2f(v0[i]) + b2f(v1[i]);
    }
    if (j < end) {
        u16x8 v = x[(size_t)csr_src[j] * 32 + sl];
#pragma unroll
        for (int i = 0; i < 8; ++i) acc[i] += b2f(v[i]);
    }
#pragma unroll
    for (int i = 0; i < 8; ++i) acc[i] += __shfl_xor(acc[i], 32, 64);
    if (grp == 0) {
        u16x8 o;
#pragma unroll
        for (int i = 0; i < 8; ++i) o[i] = f2b(acc[i]);
        out[off] = o;
    }
}

// D=128: 16 chunks -> 4 edge-groups of 16 lanes.
__global__ __launch_bounds__(256) void agg128_bf16(
    const u16x8* __restrict__ x, const int* __restrict__ row_ptr,
    const int* __restrict__ csr_src, const float* __restrict__ eps_ptr,
    u16x8* __restrict__ out, int Nn)
{
    int n = blockIdx.x * 4 + (threadIdx.x >> 6);
    if (n >= Nn) return;
    int lane = threadIdx.x & 63;
    int grp = lane >> 4;       // 0..3
    int sl  = lane & 15;
    size_t off = (size_t)n * 16 + sl;
    float acc[8];
    if (grp == 0) {
        float e1 = 1.0f + (eps_ptr ? *eps_ptr : 0.0f);
        u16x8 xv = x[off];
#pragma unroll
        for (int i = 0; i < 8; ++i) acc[i] = e1 * b2f(xv[i]);
    } else {
#pragma unroll
        for (int i = 0; i < 8; ++i) acc[i] = 0.0f;
    }
    int end = row_ptr[n + 1];
    int j = row_ptr[n] + grp;
    for (; j + 4 < end; j += 8) {           // 2 edges/group/iter
        int s0 = csr_src[j], s1 = csr_src[j + 4];
        u16x8 v0 = x[(size_t)s0 * 16 + sl];
        u16x8 v1 = x[(size_t)s1 * 16 + sl];
#pragma unroll
        for (int i = 0; i < 8; ++i) acc[i] += b2f(v0[i]) + b2f(v1[i]);
    }
    if (j < end) {
        u16x8 v = x[(size_t)csr_src[j] * 16 + sl];
#pragma unroll
        for (int i = 0; i < 8; ++i) acc[i] += b2f(v[i]);
    }
#pragma unroll
    for (int i = 0; i < 8; ++i) {
        acc[i] += __shfl_xor(acc[i], 16, 64);
        acc[i] += __shfl_xor(acc[i], 32, 64);
    }
    if (grp == 0) {
        u16x8 o;
#pragma unroll
        for (int i = 0; i < 8; ++i) o[i] = f2b(acc[i]);
        out[off] = o;
    }
}

// ================= bf16 MFMA GEMM =================
// C[M,NC] = A[M,K](bf16) @ Wt[NC,K](bf16)^T  (+bias; FUSE 0=ReLU,1=BN+LReLU,2=none)
// WM*WN waves; each wave a 64x64 sub-tile (4x4 frags of 16x16x32). BK=64.
// LDS [rows][64] bf16, XOR-swizzled 16B granules: (row, cb^(row&7)).
// global_load_lds(16B): linear LDS dest + inverse-swizzled global src.
using bf16x8 = __attribute__((ext_vector_type(8))) short;
using f32x4  = __attribute__((ext_vector_type(4))) float;

__device__ inline void gload_lds16(const void* g, void* l) {
    __builtin_amdgcn_global_load_lds(
        (const __attribute__((address_space(1))) u32*)g,
        (__attribute__((address_space(3))) u32*)l, 16, 0, 0);
}

template <int K, int BM, int BN, int WM, int WN, int FUSE, bool OUT_F32>
__global__ __launch_bounds__(WM* WN * 64) void gemm_mfma(
    const u16* __restrict__ A, const u16* __restrict__ Wt,
    const float* __restrict__ bias,
    const float* __restrict__ bn_g, const float* __restrict__ bn_b,
    const float* __restrict__ bn_m, const float* __restrict__ bn_v,
    void* __restrict__ Cout, int M, int NC)
{
    __shared__ u16 As[BM * 64];
    __shared__ u16 Bs[BN * 64];

    constexpr int NW = WM * WN;
    const int tid = threadIdx.x;
    const int wave = tid >> 6;
    const int lane = tid & 63;
    const int wm = wave / WN;
    const int wn = wave % WN;
    const int m0 = blockIdx.x * BM;
    const int n0 = blockIdx.y * BN;
    const int l15 = lane & 15;
    const int l4  = lane >> 4;

    f32x4 acc[4][4] = {};

    for (int k0 = 0; k0 < K; k0 += 64) {
        constexpr int AIW = (BM / 8) / NW;
#pragma unroll
        for (int i = 0; i < AIW; ++i) {
            int inst = wave * AIW + i;
            int g = inst * 64 + lane;
            int row = g >> 3;
            int cb = (g & 7) ^ (row & 7);
            int grow = m0 + row;
            if (grow >= M) grow = M - 1;
            gload_lds16(A + (size_t)grow * K + k0 + cb * 8, As + inst * 512);
        }
        constexpr int BIW = (BN / 8) / NW;
#pragma unroll
        for (int i = 0; i < BIW; ++i) {
            int inst = wave * BIW + i;
            int g = inst * 64 + lane;
            int row = g >> 3;
            int cb = (g & 7) ^ (row & 7);
            gload_lds16(Wt + (size_t)(n0 + row) * K + k0 + cb * 8, Bs + inst * 512);
        }
        __syncthreads();

#pragma unroll
        for (int kk = 0; kk < 2; ++kk) {
            bf16x8 af[4], bf[4];
#pragma unroll
            for (int m = 0; m < 4; ++m) {
                int row = wm * 64 + m * 16 + l15;
                int cb = kk * 4 + l4;
                af[m] = *(const bf16x8*)(As + row * 64 + ((cb ^ (row & 7)) * 8));
            }
#pragma unroll
            for (int n = 0; n < 4; ++n) {
                int row = wn * 64 + n * 16 + l15;
                int cb = kk * 4 + l4;
                bf[n] = *(const bf16x8*)(Bs + row * 64 + ((cb ^ (row & 7)) * 8));
            }
#pragma unroll
            for (int m = 0; m < 4; ++m)
#pragma unroll
                for (int n = 0; n < 4; ++n)
                    acc[m][n] = __builtin_amdgcn_mfma_f32_16x16x32_bf16(
                        af[m], bf[n], acc[m][n], 0, 0, 0);
        }
        __syncthreads();
    }

#pragma unroll
    for (int n = 0; n < 4; ++n) {
        int col = n0 + wn * 64 + n * 16 + l15;
        float bv = bias[col];
        float sc = 1.0f, sh = 0.0f;
        if (FUSE == 1) {
            float g = bn_g[col], be = bn_b[col], mm = bn_m[col], vv = bn_v[col];
            sc = g * rsqrtf(vv + 1e-5f);
            sh = be - mm * sc;
        }
#pragma unroll
        for (int m = 0; m < 4; ++m) {
            int rb = m0 + wm * 64 + m * 16 + l4 * 4;
#pragma unroll
            for (int j = 0; j < 4; ++j) {
                int gm = rb + j;
                if (gm >= M) continue;
                float v = acc[m][n][j] + bv;
                if (FUSE == 0) v = fmaxf(v, 0.0f);
                else if (FUSE == 1) {
                    v = fmaf(v, sc, sh);
                    v = v >= 0.0f ? v : 0.01f * v;
                }
                if (OUT_F32) ((float*)Cout)[(size_t)gm * NC + col] = v;
                else         ((u16*)Cout)[(size_t)gm * NC + col] = f2b(v);
            }
        }
    }
}

extern "C" void kernel_launch(void* const* d_in, const int* in_sizes, int n_in,
                              void* d_out, int out_size, void* d_ws, size_t ws_size,
                              hipStream_t stream)
{
    const float* x    = (const float*)d_in[0];
    const int*   ei   = (const int*)d_in[1];     // int32: [src(E), dst(E)]
    const float* eps0 = (const float*)d_in[2];
    const float* W01  = (const float*)d_in[3];
    const float* b01  = (const float*)d_in[4];
    const float* W02  = (const float*)d_in[5];
    const float* b02  = (const float*)d_in[6];
    const float* W11  = (const float*)d_in[7];
    const float* b11  = (const float*)d_in[8];
    const float* W12  = (const float*)d_in[9];
    const float* b12  = (const float*)d_in[10];
    const float* eps2 = (const float*)d_in[11];
    const float* W21  = (const float*)d_in[12];
    const float* b21  = (const float*)d_in[13];
    const float* W22  = (const float*)d_in[14];
    const float* b22  = (const float*)d_in[15];
    const float* bn_g = (const float*)d_in[16];
    const float* bn_b = (const float*)d_in[17];
    const float* bn_m = (const float*)d_in[18];
    const float* bn_v = (const float*)d_in[19];

    const int Nn = in_sizes[0] / IN_F;   // 50000
    const int E  = in_sizes[1] / 2;      // 600000

    // ---- workspace carve-up ----
    u16* P = (u16*)d_ws;
    u16* Q = P + (size_t)Nn * HID;
    u16* Xb = Q + (size_t)Nn * HID;
    u16* Wt01 = Xb + (size_t)Nn * IN_F;
    u16* Wt02 = Wt01 + HID * IN_F;
    u16* Wt11 = Wt02 + HID * HID;
    u16* Wt12 = Wt11 + HID * HID;
    u16* Wt21 = Wt12 + HID * HID;
    u16* Wt22 = Wt21 + HID * HID;
    int* row_ptr = (int*)(Wt22 + OUT_F * HID);
    int* cursor  = row_ptr + (Nn + 1);
    int* deg     = cursor + Nn;
    int* blksum  = deg + Nn;
    int* csr_src = blksum + 1024;

    dim3 blk(256);
    const int nwave_blocks = cdiv_i(Nn, 4);
    const int nscan = cdiv_i(Nn, 1024);

    // ---- CSR build (by dst), two-level scan ----
    hipMemsetAsync(deg, 0, (size_t)Nn * sizeof(int), stream);
    deg_count_kernel<<<cdiv_i(E, 256), blk, 0, stream>>>(ei, deg, E);
    block_scan_kernel<<<nscan, 1024, 0, stream>>>(deg, row_ptr, blksum, Nn);
    scan_blksums_kernel<<<1, 1024, 0, stream>>>(blksum, nscan);
    add_offsets_kernel<<<cdiv_i(Nn + 1, 1024), 1024, 0, stream>>>(
        row_ptr, cursor, blksum, Nn, E);
    csr_fill_kernel<<<cdiv_i(E, 256), blk, 0, stream>>>(ei, cursor, csr_src, E);

    // ---- convert x and weights to bf16 ----
    xconv_kernel<<<cdiv_i((long long)Nn * IN_F / 4, 256), blk, 0, stream>>>(
        (const float4*)x, (ushort4*)Xb, (long long)Nn * IN_F / 4);
    wconv_all_kernel<<<cdiv_i(32768 + 4 * 65536 + 16384, 256), blk, 0, stream>>>(
        W01, W02, W11, W12, W21, W22, Wt01, Wt02, Wt11, Wt12, Wt21, Wt22);

    const dim3 gA(cdiv_i(Nn, 128), 1);   // 128x256 tiles (BN=256 covers NC)
    const dim3 gF(cdiv_i(Nn, 256), 1);   // 256x64 tile, NC=64
    const dim3 blk512(512);

    // ================= layer 0 (in=128) =================
    agg128_bf16<<<nwave_blocks, blk, 0, stream>>>(
        (const u16x8*)Xb, row_ptr, csr_src, eps0, (u16x8*)P, Nn);
    gemm_mfma<128, 128, 256, 2, 4, 0, false><<<gA, blk512, 0, stream>>>(
        P, Wt01, b01, nullptr, nullptr, nullptr, nullptr, Q, Nn, HID);
    gemm_mfma<256, 128, 256, 2, 4, 1, false><<<gA, blk512, 0, stream>>>(
        Q, Wt02, b02, bn_g, bn_b, bn_m, bn_v, P, Nn, HID);

    // ================= layer 1 =================
    agg256_bf16<<<nwave_blocks, blk, 0, stream>>>(
        (const u16x8*)P, row_ptr, csr_src, nullptr, (u16x8*)Q, Nn);
    gemm_mfma<256, 128, 256, 2, 4, 0, false><<<gA, blk512, 0, stream>>>(
        Q, Wt11, b11, nullptr, nullptr, nullptr, nullptr, P, Nn, HID);
    gemm_mfma<256, 128, 256, 2, 4, 1, false><<<gA, blk512, 0, stream>>>(
        P, Wt12, b12, bn_g, bn_b, bn_m, bn_v, Q, Nn, HID);

    // ================= layer 2 (out=64) =================
    agg256_bf16<<<nwave_blocks, blk, 0, stream>>>(
        (const u16x8*)Q, row_ptr, csr_src, eps2, (u16x8*)P, Nn);
    gemm_mfma<256, 128, 256, 2, 4, 0, false><<<gA, blk512, 0, stream>>>(
        P, Wt21, b21, nullptr, nullptr, nullptr, nullptr, Q, Nn, HID);
    gemm_mfma<256, 256, 64, 4, 1, 2, true><<<gF, blk, 0, stream>>>(
        Q, Wt22, b22, nullptr, nullptr, nullptr, nullptr, d_out, Nn, OUT_F);
}

// Round 7
// 313.214 us; speedup vs baseline: 17.7693x; 1.0983x over previous
//
#include <hip/hip_runtime.h>

typedef unsigned short u16;
typedef unsigned int u32;
typedef __attribute__((ext_vector_type(8))) unsigned short u16x8;

constexpr int IN_F = 128;
constexpr int HID  = 256;
constexpr int OUT_F = 64;

static inline int cdiv_i(long long a, long long b) { return (int)((a + b - 1) / b); }

__device__ inline float b2f(u16 h) { return __uint_as_float(((u32)h) << 16); }
__device__ inline u16 f2b(float f) {
    u32 u = __float_as_uint(f);
    u32 r = (u + 0x7FFFu + ((u >> 16) & 1u)) >> 16;   // RNE
    return (u16)r;
}
__device__ inline float4 ld4(const float* p) { return *reinterpret_cast<const float4*>(p); }

// ================= CSR build =================
__global__ __launch_bounds__(256) void deg_count_kernel(
    const int* __restrict__ ei, int* __restrict__ deg, int E)
{
    int e = blockIdx.x * blockDim.x + threadIdx.x;
    if (e >= E) return;
    atomicAdd(&deg[ei[E + e]], 1);
}

__global__ __launch_bounds__(1024) void block_scan_kernel(
    const int* __restrict__ deg, int* __restrict__ row_ptr,
    int* __restrict__ blksum, int Nn)
{
    __shared__ int buf[1024];
    int i = blockIdx.x * 1024 + threadIdx.x;
    int v = (i < Nn) ? deg[i] : 0;
    buf[threadIdx.x] = v;
    __syncthreads();
    for (int off = 1; off < 1024; off <<= 1) {
        int t = (threadIdx.x >= off) ? buf[threadIdx.x - off] : 0;
        __syncthreads();
        buf[threadIdx.x] += t;
        __syncthreads();
    }
    if (i < Nn) row_ptr[i] = buf[threadIdx.x] - v;   // local exclusive
    if (threadIdx.x == 1023) blksum[blockIdx.x] = buf[1023];
}

__global__ __launch_bounds__(1024) void scan_blksums_kernel(
    int* __restrict__ blksum, int nblk)
{
    __shared__ int buf[1024];
    int v = (threadIdx.x < nblk) ? blksum[threadIdx.x] : 0;
    buf[threadIdx.x] = v;
    __syncthreads();
    for (int off = 1; off < 1024; off <<= 1) {
        int t = (threadIdx.x >= off) ? buf[threadIdx.x - off] : 0;
        __syncthreads();
        buf[threadIdx.x] += t;
        __syncthreads();
    }
    if (threadIdx.x < nblk) blksum[threadIdx.x] = buf[threadIdx.x] - v;  // exclusive
}

__global__ __launch_bounds__(1024) void add_offsets_kernel(
    int* __restrict__ row_ptr, int* __restrict__ cursor,
    const int* __restrict__ blksum, int Nn, int E)
{
    int i = blockIdx.x * 1024 + threadIdx.x;
    if (i < Nn) {
        int r = row_ptr[i] + blksum[i >> 10];
        row_ptr[i] = r;
        cursor[i]  = r;
    } else if (i == Nn) {
        row_ptr[Nn] = E;
    }
}

__global__ __launch_bounds__(256) void csr_fill_kernel(
    const int* __restrict__ ei, int* __restrict__ cursor,
    int* __restrict__ csr_src, int E)
{
    int e = blockIdx.x * blockDim.x + threadIdx.x;
    if (e >= E) return;
    int d = ei[E + e];
    int pos = atomicAdd(&cursor[d], 1);
    csr_src[pos] = ei[e];
}

// ================= conversions =================
__global__ __launch_bounds__(256) void xconv_kernel(
    const float4* __restrict__ in, ushort4* __restrict__ out, long long total4)
{
    long long i = (long long)blockIdx.x * blockDim.x + threadIdx.x;
    if (i >= total4) return;
    float4 v = in[i];
    ushort4 o;
    o.x = f2b(v.x); o.y = f2b(v.y); o.z = f2b(v.z); o.w = f2b(v.w);
    out[i] = o;
}

// All six weights fp32 [K][NC] -> bf16 [NC][K], one launch.
__global__ __launch_bounds__(256) void wconv_all_kernel(
    const float* __restrict__ W01, const float* __restrict__ W02,
    const float* __restrict__ W11, const float* __restrict__ W12,
    const float* __restrict__ W21, const float* __restrict__ W22,
    u16* __restrict__ Wt01, u16* __restrict__ Wt02,
    u16* __restrict__ Wt11, u16* __restrict__ Wt12,
    u16* __restrict__ Wt21, u16* __restrict__ Wt22)
{
    int id = blockIdx.x * blockDim.x + threadIdx.x;
    const float* W; u16* Wt; int kshift, NC;
    if (id < 32768)                  { W = W01; Wt = Wt01; kshift = 7; NC = 256; }
    else if ((id -= 32768) < 65536)  { W = W02; Wt = Wt02; kshift = 8; NC = 256; }
    else if ((id -= 65536) < 65536)  { W = W11; Wt = Wt11; kshift = 8; NC = 256; }
    else if ((id -= 65536) < 65536)  { W = W12; Wt = Wt12; kshift = 8; NC = 256; }
    else if ((id -= 65536) < 65536)  { W = W21; Wt = Wt21; kshift = 8; NC = 256; }
    else if ((id -= 65536) < 16384)  { W = W22; Wt = Wt22; kshift = 8; NC = 64;  }
    else return;
    int K = 1 << kshift;
    int n = id >> kshift;
    int k = id & (K - 1);
    Wt[id] = f2b(W[(long long)k * NC + n]);
}

// ================= gather aggregation (bf16, fp32 accum) =================
__global__ __launch_bounds__(256) void agg256_bf16(
    const u16x8* __restrict__ x, const int* __restrict__ row_ptr,
    const int* __restrict__ csr_src, const float* __restrict__ eps_ptr,
    u16x8* __restrict__ out, int Nn)
{
    int n = blockIdx.x * 4 + (threadIdx.x >> 6);
    if (n >= Nn) return;
    int lane = threadIdx.x & 63;
    int grp = lane >> 5;       // 0/1
    int sl  = lane & 31;       // chunk index
    size_t off = (size_t)n * 32 + sl;
    float acc[8];
    if (grp == 0) {
        float e1 = 1.0f + (eps_ptr ? *eps_ptr : 0.0f);
        u16x8 xv = x[off];
#pragma unroll
        for (int i = 0; i < 8; ++i) acc[i] = e1 * b2f(xv[i]);
    } else {
#pragma unroll
        for (int i = 0; i < 8; ++i) acc[i] = 0.0f;
    }
    int end = row_ptr[n + 1];
    int j = row_ptr[n] + grp;
    for (; j + 2 < end; j += 4) {
        int s0 = csr_src[j], s1 = csr_src[j + 2];
        u16x8 v0 = x[(size_t)s0 * 32 + sl];
        u16x8 v1 = x[(size_t)s1 * 32 + sl];
#pragma unroll
        for (int i = 0; i < 8; ++i) acc[i] += b2f(v0[i]) + b2f(v1[i]);
    }
    if (j < end) {
        u16x8 v = x[(size_t)csr_src[j] * 32 + sl];
#pragma unroll
        for (int i = 0; i < 8; ++i) acc[i] += b2f(v[i]);
    }
#pragma unroll
    for (int i = 0; i < 8; ++i) acc[i] += __shfl_xor(acc[i], 32, 64);
    if (grp == 0) {
        u16x8 o;
#pragma unroll
        for (int i = 0; i < 8; ++i) o[i] = f2b(acc[i]);
        out[off] = o;
    }
}

__global__ __launch_bounds__(256) void agg128_bf16(
    const u16x8* __restrict__ x, const int* __restrict__ row_ptr,
    const int* __restrict__ csr_src, const float* __restrict__ eps_ptr,
    u16x8* __restrict__ out, int Nn)
{
    int n = blockIdx.x * 4 + (threadIdx.x >> 6);
    if (n >= Nn) return;
    int lane = threadIdx.x & 63;
    int grp = lane >> 4;       // 0..3
    int sl  = lane & 15;
    size_t off = (size_t)n * 16 + sl;
    float acc[8];
    if (grp == 0) {
        float e1 = 1.0f + (eps_ptr ? *eps_ptr : 0.0f);
        u16x8 xv = x[off];
#pragma unroll
        for (int i = 0; i < 8; ++i) acc[i] = e1 * b2f(xv[i]);
    } else {
#pragma unroll
        for (int i = 0; i < 8; ++i) acc[i] = 0.0f;
    }
    int end = row_ptr[n + 1];
    int j = row_ptr[n] + grp;
    for (; j + 4 < end; j += 8) {
        int s0 = csr_src[j], s1 = csr_src[j + 4];
        u16x8 v0 = x[(size_t)s0 * 16 + sl];
        u16x8 v1 = x[(size_t)s1 * 16 + sl];
#pragma unroll
        for (int i = 0; i < 8; ++i) acc[i] += b2f(v0[i]) + b2f(v1[i]);
    }
    if (j < end) {
        u16x8 v = x[(size_t)csr_src[j] * 16 + sl];
#pragma unroll
        for (int i = 0; i < 8; ++i) acc[i] += b2f(v[i]);
    }
#pragma unroll
    for (int i = 0; i < 8; ++i) {
        acc[i] += __shfl_xor(acc[i], 16, 64);
        acc[i] += __shfl_xor(acc[i], 32, 64);
    }
    if (grp == 0) {
        u16x8 o;
#pragma unroll
        for (int i = 0; i < 8; ++i) o[i] = f2b(acc[i]);
        out[off] = o;
    }
}

// ================= fused 2-layer MLP (per GIN layer) =================
// Per 64-row block:
//   phase 1: H = relu(A @ W1t^T + b1)   -> LDS (64 x 256 bf16, swizzled)
//   phase 2: C = H @ W2t^T + b2 [BN+LReLU or none] -> global
// Swapped-operand MFMA: D = mfma(P,Q): P-row -> (l>>4)*4+j, Q-row -> l&15
// (mapping verified by rounds 4-6 kernels). We use P=weight, Q=activation so
// each lane holds 4 consecutive out-cols of one row -> 8B/16B vector stores.
// LDS tiles [rows][64] (stride 128B) XOR-swizzled by 16B granule: (row, g^(row&7));
// H [64][256] (stride 512B) swizzled the same way with g in [0,32).
using bf16x8 = __attribute__((ext_vector_type(8))) short;
using f32x4  = __attribute__((ext_vector_type(4))) float;

__device__ inline void gload_lds16(const void* g, void* l) {
    __builtin_amdgcn_global_load_lds(
        (const __attribute__((address_space(1))) u32*)g,
        (__attribute__((address_space(3))) u32*)l, 16, 0, 0);
}

template <int KIN, int NOUT, int FUSE2, bool OF32>
__global__ __launch_bounds__(512) void mlp_fused(
    const u16* __restrict__ A, const u16* __restrict__ W1t,
    const float* __restrict__ b1,
    const u16* __restrict__ W2t, const float* __restrict__ b2,
    const float* __restrict__ bn_g, const float* __restrict__ bn_b,
    const float* __restrict__ bn_m, const float* __restrict__ bn_v,
    void* __restrict__ Cout, int M)
{
    __shared__ u16 lds[57344];          // 112 KB
    u16* Ab = lds;                      // [2][4096]  : 64 rows x 64 k
    u16* Wb = lds + 8192;               // [2][16384] : up to 256 rows x 64 k
    u16* Hl = lds + 8192 + 32768;       // [16384]    : 64 rows x 256 k

    const int tid  = threadIdx.x;
    const int wv   = tid >> 6;
    const int lane = tid & 63;
    const int l15  = lane & 15, l4 = lane >> 4;
    const int m0   = blockIdx.x * 64;

    constexpr int KT1 = KIN / 64;

    auto stageA = [&](int kt, int buf) {
        int inst = wv;                       // 8 instrs, 1 per wave
        int g = inst * 64 + lane;
        int row = g >> 3;
        int cb = (g & 7) ^ (row & 7);
        int grow = m0 + row; if (grow >= M) grow = M - 1;
        gload_lds16(A + (size_t)grow * KIN + kt * 64 + cb * 8,
                    Ab + buf * 4096 + inst * 512);
    };
    auto stageW1 = [&](int kt, int buf) {
#pragma unroll
        for (int i = 0; i < 4; ++i) {        // 32 instrs
            int inst = wv * 4 + i;
            int g = inst * 64 + lane;
            int row = g >> 3;
            int cb = (g & 7) ^ (row & 7);
            gload_lds16(W1t + (size_t)row * KIN + kt * 64 + cb * 8,
                        Wb + buf * 16384 + inst * 512);
        }
    };
    auto stageW2 = [&](int kt, int buf) {
        constexpr int I = NOUT / 64;
#pragma unroll
        for (int i = 0; i < I; ++i) {
            int inst = wv * I + i;
            int g = inst * 64 + lane;
            int row = g >> 3;
            int cb = (g & 7) ^ (row & 7);
            gload_lds16(W2t + (size_t)row * 256 + kt * 64 + cb * 8,
                        Wb + buf * 16384 + inst * 512);
        }
    };

    // ---------------- phase 1 ----------------
    f32x4 acc1[4][2] = {};
    int cur = 0;
    stageA(0, 0); stageW1(0, 0);
    __syncthreads();
#pragma unroll
    for (int kt = 0; kt < KT1; ++kt) {
        if (kt + 1 < KT1) { stageA(kt + 1, cur ^ 1); stageW1(kt + 1, cur ^ 1); }
        else              { stageW2(0, cur ^ 1); }
#pragma unroll
        for (int kk = 0; kk < 2; ++kk) {
            int cb = kk * 4 + l4;
            bf16x8 af[4], wf[2];
#pragma unroll
            for (int m = 0; m < 4; ++m) {
                int row = m * 16 + l15;
                af[m] = *(const bf16x8*)(Ab + cur * 4096 + row * 64 + ((cb ^ (row & 7)) * 8));
            }
#pragma unroll
            for (int n = 0; n < 2; ++n) {
                int wrow = wv * 32 + n * 16 + l15;
                wf[n] = *(const bf16x8*)(Wb + cur * 16384 + wrow * 64 + ((cb ^ (wrow & 7)) * 8));
            }
#pragma unroll
            for (int m = 0; m < 4; ++m)
#pragma unroll
                for (int n = 0; n < 2; ++n)
                    acc1[m][n] = __builtin_amdgcn_mfma_f32_16x16x32_bf16(
                        wf[n], af[m], acc1[m][n], 0, 0, 0);
        }
        if (kt + 1 < KT1) { __syncthreads(); cur ^= 1; }
    }
    // H = relu(acc1 + b1) -> LDS  (W2 k0 staging is in flight into cur^1)
#pragma unroll
    for (int m = 0; m < 4; ++m) {
        int arow = m * 16 + l15;
#pragma unroll
        for (int n = 0; n < 2; ++n) {
            int hcol = wv * 32 + n * 16 + l4 * 4;
            float4 bv = ld4(b1 + hcol);
            float v0 = fmaxf(acc1[m][n][0] + bv.x, 0.f);
            float v1 = fmaxf(acc1[m][n][1] + bv.y, 0.f);
            float v2 = fmaxf(acc1[m][n][2] + bv.z, 0.f);
            float v3 = fmaxf(acc1[m][n][3] + bv.w, 0.f);
            u32 p0 = (u32)f2b(v0) | ((u32)f2b(v1) << 16);
            u32 p1 = (u32)f2b(v2) | ((u32)f2b(v3) << 16);
            int g = hcol >> 3;
            u16* dst = Hl + arow * 256 + ((g ^ (arow & 7)) * 8) + (hcol & 7);
            *reinterpret_cast<uint2*>(dst) = make_uint2(p0, p1);
        }
    }
    __syncthreads();       // H visible + W2(0) staged
    cur ^= 1;              // Wb[cur] = W2 k-step 0

    // ---------------- phase 2 ----------------
    constexpr int MF2 = (NOUT == 256) ? 4 : 2;
    constexpr int NF2 = (NOUT == 256) ? 2 : 1;
    const int rbase = (NOUT == 256) ? 0 : (wv >> 2) * 32;
    const int cbase = (NOUT == 256) ? wv * 32 : (wv & 3) * 16;

    f32x4 acc2[MF2][NF2] = {};
#pragma unroll
    for (int kt = 0; kt < 4; ++kt) {
        if (kt + 1 < 4) stageW2(kt + 1, cur ^ 1);
#pragma unroll
        for (int kk = 0; kk < 2; ++kk) {
            int cbg = kt * 8 + kk * 4 + l4;    // H granule (0..31)
            int cbw = kk * 4 + l4;             // W tile granule (0..7)
            bf16x8 hf[MF2], wf[NF2];
#pragma unroll
            for (int m = 0; m < MF2; ++m) {
                int row = rbase + m * 16 + l15;
                hf[m] = *(const bf16x8*)(Hl + row * 256 + ((cbg ^ (row & 7)) * 8));
            }
#pragma unroll
            for (int n = 0; n < NF2; ++n) {
                int wrow = cbase + n * 16 + l15;
                wf[n] = *(const bf16x8*)(Wb + cur * 16384 + wrow * 64 + ((cbw ^ (wrow & 7)) * 8));
            }
#pragma unroll
            for (int m = 0; m < MF2; ++m)
#pragma unroll
                for (int n = 0; n < NF2; ++n)
                    acc2[m][n] = __builtin_amdgcn_mfma_f32_16x16x32_bf16(
                        wf[n], hf[m], acc2[m][n], 0, 0, 0);
        }
        if (kt + 1 < 4) { __syncthreads(); cur ^= 1; }
    }

    // ---------------- epilogue ----------------
#pragma unroll
    for (int m = 0; m < MF2; ++m) {
        int grow = m0 + rbase + m * 16 + l15;
        if (grow >= M) continue;
#pragma unroll
        for (int n = 0; n < NF2; ++n) {
            int col = cbase + n * 16 + l4 * 4;
            float4 bv = ld4(b2 + col);
            float v0 = acc2[m][n][0] + bv.x;
            float v1 = acc2[m][n][1] + bv.y;
            float v2 = acc2[m][n][2] + bv.z;
            float v3 = acc2[m][n][3] + bv.w;
            if (FUSE2 == 1) {
                float4 g = ld4(bn_g + col), be = ld4(bn_b + col);
                float4 mm = ld4(bn_m + col), vv = ld4(bn_v + col);
                float s0 = g.x * rsqrtf(vv.x + 1e-5f);
                float s1 = g.y * rsqrtf(vv.y + 1e-5f);
                float s2 = g.z * rsqrtf(vv.z + 1e-5f);
                float s3 = g.w * rsqrtf(vv.w + 1e-5f);
                v0 = fmaf(v0, s0, be.x - mm.x * s0);
                v1 = fmaf(v1, s1, be.y - mm.y * s1);
                v2 = fmaf(v2, s2, be.z - mm.z * s2);
                v3 = fmaf(v3, s3, be.w - mm.w * s3);
                v0 = v0 >= 0.f ? v0 : 0.01f * v0;
                v1 = v1 >= 0.f ? v1 : 0.01f * v1;
                v2 = v2 >= 0.f ? v2 : 0.01f * v2;
                v3 = v3 >= 0.f ? v3 : 0.01f * v3;
            }
            if (OF32) {
                float4 o = make_float4(v0, v1, v2, v3);
                *reinterpret_cast<float4*>((float*)Cout + (size_t)grow * NOUT + col) = o;
            } else {
                u32 p0 = (u32)f2b(v0) | ((u32)f2b(v1) << 16);
                u32 p1 = (u32)f2b(v2) | ((u32)f2b(v3) << 16);
                *reinterpret_cast<uint2*>((u16*)Cout + (size_t)grow * NOUT + col) =
                    make_uint2(p0, p1);
            }
        }
    }
}

extern "C" void kernel_launch(void* const* d_in, const int* in_sizes, int n_in,
                              void* d_out, int out_size, void* d_ws, size_t ws_size,
                              hipStream_t stream)
{
    const float* x    = (const float*)d_in[0];
    const int*   ei   = (const int*)d_in[1];     // int32: [src(E), dst(E)]
    const float* eps0 = (const float*)d_in[2];
    const float* W01  = (const float*)d_in[3];
    const float* b01  = (const float*)d_in[4];
    const float* W02  = (const float*)d_in[5];
    const float* b02  = (const float*)d_in[6];
    const float* W11  = (const float*)d_in[7];
    const float* b11  = (const float*)d_in[8];
    const float* W12  = (const float*)d_in[9];
    const float* b12  = (const float*)d_in[10];
    const float* eps2 = (const float*)d_in[11];
    const float* W21  = (const float*)d_in[12];
    const float* b21  = (const float*)d_in[13];
    const float* W22  = (const float*)d_in[14];
    const float* b22  = (const float*)d_in[15];
    const float* bn_g = (const float*)d_in[16];
    const float* bn_b = (const float*)d_in[17];
    const float* bn_m = (const float*)d_in[18];
    const float* bn_v = (const float*)d_in[19];

    const int Nn = in_sizes[0] / IN_F;   // 50000
    const int E  = in_sizes[1] / 2;      // 600000

    // ---- workspace carve-up ----
    u16* P = (u16*)d_ws;
    u16* Q = P + (size_t)Nn * HID;
    u16* Xb = Q + (size_t)Nn * HID;
    u16* Wt01 = Xb + (size_t)Nn * IN_F;
    u16* Wt02 = Wt01 + HID * IN_F;
    u16* Wt11 = Wt02 + HID * HID;
    u16* Wt12 = Wt11 + HID * HID;
    u16* Wt21 = Wt12 + HID * HID;
    u16* Wt22 = Wt21 + HID * HID;
    int* row_ptr = (int*)(Wt22 + OUT_F * HID);
    int* cursor  = row_ptr + (Nn + 1);
    int* deg     = cursor + Nn;
    int* blksum  = deg + Nn;
    int* csr_src = blksum + 1024;

    dim3 blk(256);
    const int nwave_blocks = cdiv_i(Nn, 4);
    const int nscan = cdiv_i(Nn, 1024);

    // ---- CSR build (by dst), two-level scan ----
    hipMemsetAsync(deg, 0, (size_t)Nn * sizeof(int), stream);
    deg_count_kernel<<<cdiv_i(E, 256), blk, 0, stream>>>(ei, deg, E);
    block_scan_kernel<<<nscan, 1024, 0, stream>>>(deg, row_ptr, blksum, Nn);
    scan_blksums_kernel<<<1, 1024, 0, stream>>>(blksum, nscan);
    add_offsets_kernel<<<cdiv_i(Nn + 1, 1024), 1024, 0, stream>>>(
        row_ptr, cursor, blksum, Nn, E);
    csr_fill_kernel<<<cdiv_i(E, 256), blk, 0, stream>>>(ei, cursor, csr_src, E);

    // ---- convert x and weights to bf16 ----
    xconv_kernel<<<cdiv_i((long long)Nn * IN_F / 4, 256), blk, 0, stream>>>(
        (const float4*)x, (ushort4*)Xb, (long long)Nn * IN_F / 4);
    wconv_all_kernel<<<cdiv_i(32768 + 4 * 65536 + 16384, 256), blk, 0, stream>>>(
        W01, W02, W11, W12, W21, W22, Wt01, Wt02, Wt11, Wt12, Wt21, Wt22);

    const int mlp_blocks = cdiv_i(Nn, 64);
    const dim3 blk512(512);

    // ================= layer 0 (in=128) =================
    agg128_bf16<<<nwave_blocks, blk, 0, stream>>>(
        (const u16x8*)Xb, row_ptr, csr_src, eps0, (u16x8*)P, Nn);
    mlp_fused<128, 256, 1, false><<<mlp_blocks, blk512, 0, stream>>>(
        P, Wt01, b01, Wt02, b02, bn_g, bn_b, bn_m, bn_v, Q, Nn);

    // ================= layer 1 =================
    agg256_bf16<<<nwave_blocks, blk, 0, stream>>>(
        (const u16x8*)Q, row_ptr, csr_src, nullptr, (u16x8*)P, Nn);
    mlp_fused<256, 256, 1, false><<<mlp_blocks, blk512, 0, stream>>>(
        P, Wt11, b11, Wt12, b12, bn_g, bn_b, bn_m, bn_v, Q, Nn);

    // ================= layer 2 (out=64) =================
    agg256_bf16<<<nwave_blocks, blk, 0, stream>>>(
        (const u16x8*)Q, row_ptr, csr_src, eps2, (u16x8*)P, Nn);
    mlp_fused<256, 64, 2, true><<<mlp_blocks, blk512, 0, stream>>>(
        P, Wt21, b21, Wt22, b22, nullptr, nullptr, nullptr, nullptr, d_out, Nn);
}